// Round 16
// baseline (1340.153 us; speedup 1.0000x reference)
//
#include <hip/hip_runtime.h>
#include <hip/hip_bf16.h>
#include <stdint.h>

#define EDIM 1024
#define DFFDIM 4096
#define NLAYER 4
#define BATCH 4
#define SEQ 1024
#define NHEAD 16
#define DHEAD 64
#define VOCAB 32000
#define MROWS (BATCH*SEQ)
#define QKVLD (3*EDIM)
#define EPSF 1e-6f
#define ALPHA 0.18033688011112043f   // 0.125 * log2(e): folded into Wq/bq

typedef float f32x4 __attribute__((ext_vector_type(4)));
typedef short s16x8 __attribute__((ext_vector_type(8)));
typedef __bf16 bf16x8 __attribute__((ext_vector_type(8)));

__device__ inline unsigned short f2bf(float f) {
  union { float f; uint32_t u; } v; v.f = f;
  uint32_t r = v.u + 0x7fffu + ((v.u >> 16) & 1u);
  return (unsigned short)(r >> 16);
}

__device__ __forceinline__ float fexp2(float x) {
  float r; asm("v_exp_f32 %0, %1" : "=v"(r) : "v"(x)); return r;
}
__device__ __forceinline__ uint32_t cvtpk(float lo, float hi) {
  uint32_t r; asm("v_cvt_pk_bf16_f32 %0, %1, %2" : "=v"(r) : "v"(lo), "v"(hi)); return r;
}

__device__ __forceinline__ void gload16(const void* g, void* l) {
  __builtin_amdgcn_global_load_lds(
      (const __attribute__((address_space(1))) void*)g,
      (__attribute__((address_space(3))) void*)l, 16, 0, 0);
}

// ---------------- embedding + positional encoding ----------------
__global__ __launch_bounds__(256) void embed_kernel(
    const int* __restrict__ tokens, const float* __restrict__ emb,
    const float* __restrict__ pe, float* __restrict__ x,
    unsigned short* __restrict__ xb) {
  const int row = blockIdx.x;
  const int s = row & (SEQ - 1);
  const int tok = tokens[row];
  const int c = threadIdx.x * 4;
  float4 ev = *(const float4*)(emb + (size_t)tok * EDIM + c);
  float4 pv = *(const float4*)(pe + (size_t)s * EDIM + c);
  float4 o;
  o.x = ev.x + pv.x; o.y = ev.y + pv.y; o.z = ev.z + pv.z; o.w = ev.w + pv.w;
  *(float4*)(x + (size_t)row * EDIM + c) = o;
  unsigned short* xr = xb + (size_t)row * EDIM + c;
  xr[0] = f2bf(o.x); xr[1] = f2bf(o.y); xr[2] = f2bf(o.z); xr[3] = f2bf(o.w);
}

// ---------------- weight transpose+convert, layer-batched via blockIdx.z ----------------
__global__ __launch_bounds__(256) void transpose_w(
    const float* __restrict__ src0, unsigned short* __restrict__ dst0,
    int N, int K, float scale, size_t srcStride, size_t dstStride) {
  const float* src = src0 + (size_t)blockIdx.z * srcStride;
  unsigned short* dst = dst0 + (size_t)blockIdx.z * dstStride;
  __shared__ float tl[64][65];
  const int t = threadIdx.x;
  const int k0 = blockIdx.x * 64, n0 = blockIdx.y * 64;
  const int c = (t & 15) * 4, r0 = t >> 4;
  #pragma unroll
  for (int i = 0; i < 4; ++i) {
    const int r = r0 + i * 16;
    float4 v = *(const float4*)(src + (size_t)(k0 + r) * N + n0 + c);
    tl[r][c] = v.x; tl[r][c + 1] = v.y; tl[r][c + 2] = v.z; tl[r][c + 3] = v.w;
  }
  __syncthreads();
  #pragma unroll
  for (int i = 0; i < 4; ++i) {
    const int n = r0 + i * 16;
    uint2 o;
    o.x = (uint32_t)f2bf(tl[c + 0][n] * scale) | ((uint32_t)f2bf(tl[c + 1][n] * scale) << 16);
    o.y = (uint32_t)f2bf(tl[c + 2][n] * scale) | ((uint32_t)f2bf(tl[c + 3][n] * scale) << 16);
    *(uint2*)(dst + (size_t)(n0 + n) * K + k0 + c) = o;
  }
}

// ---------------- pack qkv bias (bq scaled by ALPHA) ----------------
__global__ __launch_bounds__(256) void pack_bias(
    const float* __restrict__ bq, const float* __restrict__ bk,
    const float* __restrict__ bv, float* __restrict__ dst) {
  const int idx = blockIdx.x * 256 + threadIdx.x;
  if (idx >= NLAYER * QKVLD) return;
  const int layer = idx / QKVLD, c = idx % QKVLD;
  float v;
  if (c < 1024)      v = bq[layer * 1024 + c] * ALPHA;
  else if (c < 2048) v = bk[layer * 1024 + c - 1024];
  else               v = bv[layer * 1024 + c - 2048];
  dst[idx] = v;
}

// ---------------- 3-deep pipelined GEMM, BK=32, counted vmcnt, supergrouped tiles ----------------
template<int BM, int OUT_BF16, int RELU, int SPLITK>
__global__ __launch_bounds__(BM * 2, (BM == 256) ? 2 : 3) void gemm3(
    const unsigned short* __restrict__ A, const unsigned short* __restrict__ Bt,
    const float* __restrict__ bias, void* __restrict__ Cout, void* __restrict__ C2,
    int Nld, int KLEN, int KLD, int NBLK, int G) {
  constexpr int BUFB = BM * 128;
  constexpr int ABYTES = BM * 64;
  constexpr int WN = (BM == 256) ? 4 : 2;
  constexpr int MF = BM / 32;
  __shared__ __attribute__((aligned(16))) char smb[3 * BUFB];
  const int t = threadIdx.x, lane = t & 63;
  const int wave = t >> 6;
  const int wr = wave / WN, wc = wave % WN;
  const int l15 = lane & 15, lg = lane >> 4;

  const int cpx = gridDim.x >> 3;
  const int bid = blockIdx.x;
  const int swz = (bid & 7) * cpx + (bid >> 3);
  const int sg = (gridDim.x / NBLK) * G;
  const int ns = swz / sg, rem = swz % sg;
  const int m0 = (rem / G) * BM;
  const int n0 = (ns * G + rem % G) * BM;
  const int koff = SPLITK ? blockIdx.y * KLEN : 0;

  f32x4 acc[MF][4];
  #pragma unroll
  for (int i = 0; i < MF; ++i)
    #pragma unroll
    for (int j = 0; j < 4; ++j)
      acc[i][j] = (f32x4){0.f, 0.f, 0.f, 0.f};

  const int srow = t >> 2;
  const int scol = (((t & 3) ^ ((t >> 3) & 3)) << 3);
  const unsigned short* agp = A  + (size_t)(m0 + srow) * KLD + scol + koff;
  const unsigned short* bgp = Bt + (size_t)(n0 + srow) * KLD + scol + koff;
  const size_t rhalf = (size_t)(BM / 2) * KLD;

  const int cxo = (lg * 16) ^ (((l15 >> 1) & 3) << 4);
  const int rdA = (wr * (BM / 2) + l15) * 64 + cxo;
  const int rdB = ABYTES + (wc * 64 + l15) * 64 + cxo;

  auto stage_tile = [&](int b, int kt) {
    const int k0 = kt * 32;
    char* d = smb + b * BUFB + t * 16;
    gload16(agp + k0, d);
    gload16(agp + rhalf + k0, d + BM * 32);
    gload16(bgp + k0, d + ABYTES);
    gload16(bgp + rhalf + k0, d + ABYTES + BM * 32);
  };

  const int NT = KLEN / 32;
  stage_tile(0, 0);
  stage_tile(1, 1);
  asm volatile("s_waitcnt vmcnt(4)" ::: "memory");
  __builtin_amdgcn_s_barrier();
  __builtin_amdgcn_sched_barrier(0);

  int bufc = 0, bufn = 2;
  for (int tt = 0; tt < NT; ++tt) {
    if (tt + 2 < NT) stage_tile(bufn, tt + 2);

    const char* ab = smb + bufc * BUFB;
    bf16x8 af[MF], bf[4];
    #pragma unroll
    for (int mf = 0; mf < MF; ++mf)
      af[mf] = *(const bf16x8*)(ab + rdA + mf * 1024);
    #pragma unroll
    for (int nf = 0; nf < 4; ++nf)
      bf[nf] = *(const bf16x8*)(ab + rdB + nf * 1024);

    __builtin_amdgcn_s_setprio(1);
    #pragma unroll
    for (int mf = 0; mf < MF; ++mf)
      #pragma unroll
      for (int nf = 0; nf < 4; ++nf)
        acc[mf][nf] = __builtin_amdgcn_mfma_f32_16x16x32_bf16(af[mf], bf[nf], acc[mf][nf], 0, 0, 0);
    __builtin_amdgcn_s_setprio(0);

    if (tt + 2 < NT)      asm volatile("s_waitcnt vmcnt(4)" ::: "memory");
    else if (tt + 1 < NT) asm volatile("s_waitcnt vmcnt(0)" ::: "memory");
    __builtin_amdgcn_sched_barrier(0);
    __builtin_amdgcn_s_barrier();
    __builtin_amdgcn_sched_barrier(0);

    bufc = (bufc == 2) ? 0 : bufc + 1;
    bufn = (bufn == 2) ? 0 : bufn + 1;
  }

  void* Cw = (SPLITK && blockIdx.y) ? C2 : Cout;
  #pragma unroll
  for (int mf = 0; mf < MF; ++mf) {
    #pragma unroll
    for (int nf = 0; nf < 4; ++nf) {
      const int col = n0 + wc * 64 + nf * 16 + l15;
      const float bv = (SPLITK && blockIdx.y) ? 0.f : bias[col];
      #pragma unroll
      for (int r = 0; r < 4; ++r) {
        const int row = m0 + wr * (BM / 2) + mf * 16 + lg * 4 + r;
        float val = acc[mf][nf][r] + bv;
        if (RELU) val = fmaxf(val, 0.f);
        if (OUT_BF16)
          ((unsigned short*)Cw)[(size_t)row * Nld + col] = f2bf(val);
        else
          ((float*)Cw)[(size_t)row * Nld + col] = val;
      }
    }
  }
}

// ---------------- flash attention, swapped QK^T, in-lane softmax, KVBLK=64 ----------------
__global__ __launch_bounds__(256) void attn_kernel(
    const unsigned short* __restrict__ qkv, unsigned short* __restrict__ ctx) {
  const int b = blockIdx.z, h = blockIdx.y;
  const int t = threadIdx.x, wave = t >> 6, lane = t & 63;
  const int l15 = lane & 15, lg = lane >> 4;
  const int qrow0 = blockIdx.x * 64 + wave * 16;
  const unsigned short* qbs = qkv + (size_t)b * SEQ * QKVLD + h * DHEAD;
  const unsigned short* kbs = qbs + EDIM;
  const unsigned short* vbs = qbs + 2 * EDIM;
  __shared__ unsigned short Ksm[64][72];
  __shared__ unsigned short VTs[64 * 64];

  const unsigned short* qp = qbs + (size_t)(qrow0 + l15) * QKVLD + lg * 8;
  bf16x8 a0 = *(const bf16x8*)qp;
  bf16x8 a1 = *(const bf16x8*)(qp + 32);

  f32x4 o[4];
  #pragma unroll
  for (int dg = 0; dg < 4; ++dg) o[dg] = (f32x4){0.f, 0.f, 0.f, 0.f};
  float m = -1e30f, ls = 0.f;

  const int sr = t >> 2;
  const int sc = (t & 3) * 16;
  const int posw = (((sr >> 4) & 1) << 5) | (((sr & 15) >> 2) << 3) | (((sr >> 5) & 1) << 2) | (sr & 3);
  const unsigned short* kgp = kbs + (size_t)sr * QKVLD + sc;
  const unsigned short* vgp = vbs + (size_t)sr * QKVLD + sc;
  const size_t tilestep = (size_t)64 * QKVLD;

  s16x8 kr0 = *(const s16x8*)kgp, kr1 = *(const s16x8*)(kgp + 8);
  s16x8 vr0 = *(const s16x8*)vgp, vr1 = *(const s16x8*)(vgp + 8);

  const int NT = SEQ / 64;
  for (int j = 0; j < NT; ++j) {
    *(s16x8*)&Ksm[sr][sc] = kr0;
    *(s16x8*)&Ksm[sr][sc + 8] = kr1;
    #pragma unroll
    for (int c = 0; c < 2; ++c) {
      s16x8 vv = c ? vr1 : vr0;
      #pragma unroll
      for (int e = 0; e < 8; ++e) {
        const int d = sc + c * 8 + e;
        const int byteo = d * 128 + ((posw * 2) ^ ((d & 7) << 4));
        *(unsigned short*)((char*)VTs + byteo) = (unsigned short)vv[e];
      }
    }
    __syncthreads();

    f32x4 s[4];
    __builtin_amdgcn_s_setprio(1);
    #pragma unroll
    for (int g = 0; g < 4; ++g) {
      bf16x8 k0 = *(const bf16x8*)&Ksm[g * 16 + l15][lg * 8];
      bf16x8 k1 = *(const bf16x8*)&Ksm[g * 16 + l15][32 + lg * 8];
      f32x4 z = {0, 0, 0, 0};
      z = __builtin_amdgcn_mfma_f32_16x16x32_bf16(k0, a0, z, 0, 0, 0);
      s[g] = __builtin_amdgcn_mfma_f32_16x16x32_bf16(k1, a1, z, 0, 0, 0);
    }
    __builtin_amdgcn_s_setprio(0);

    if (j + 1 < NT) {
      const unsigned short* kn = kgp + (size_t)(j + 1) * tilestep;
      const unsigned short* vn = vgp + (size_t)(j + 1) * tilestep;
      kr0 = *(const s16x8*)kn; kr1 = *(const s16x8*)(kn + 8);
      vr0 = *(const s16x8*)vn; vr1 = *(const s16x8*)(vn + 8);
    }

    float mx = s[0][0];
    #pragma unroll
    for (int g = 0; g < 4; ++g)
      #pragma unroll
      for (int r = 0; r < 4; ++r) mx = fmaxf(mx, s[g][r]);
    mx = fmaxf(mx, __shfl_xor(mx, 16));
    mx = fmaxf(mx, __shfl_xor(mx, 32));

    if (__any(mx > m + 8.f)) {
      const float mn = fmaxf(m, mx);
      const float scl = fexp2(m - mn);
      m = mn;
      ls *= scl;
      #pragma unroll
      for (int dg = 0; dg < 4; ++dg)
        #pragma unroll
        for (int r = 0; r < 4; ++r) o[dg][r] *= scl;
    }
    #pragma unroll
    for (int g = 0; g < 4; ++g)
      #pragma unroll
      for (int r = 0; r < 4; ++r) s[g][r] = fexp2(s[g][r] - m);

    float rs = 0.f;
    #pragma unroll
    for (int g = 0; g < 4; ++g)
      rs += (s[g][0] + s[g][1]) + (s[g][2] + s[g][3]);
    rs += __shfl_xor(rs, 16);
    rs += __shfl_xor(rs, 32);
    ls += rs;

    union { uint32_t u[4]; bf16x8 v; } pb0, pb1;
    pb0.u[0] = cvtpk(s[0][0], s[0][1]); pb0.u[1] = cvtpk(s[0][2], s[0][3]);
    pb0.u[2] = cvtpk(s[2][0], s[2][1]); pb0.u[3] = cvtpk(s[2][2], s[2][3]);
    pb1.u[0] = cvtpk(s[1][0], s[1][1]); pb1.u[1] = cvtpk(s[1][2], s[1][3]);
    pb1.u[2] = cvtpk(s[3][0], s[3][1]); pb1.u[3] = cvtpk(s[3][2], s[3][3]);

    auto vld = [&](int dg, int c) {
      const int byteo = (dg * 16 + l15) * 128 + ((c * 64 + lg * 16) ^ ((l15 & 7) << 4));
      return *(const bf16x8*)((const char*)VTs + byteo);
    };
    __builtin_amdgcn_s_setprio(1);
    #pragma unroll
    for (int dg = 0; dg < 4; ++dg)
      o[dg] = __builtin_amdgcn_mfma_f32_16x16x32_bf16(vld(dg, 0), pb0.v, o[dg], 0, 0, 0);
    #pragma unroll
    for (int dg = 0; dg < 4; ++dg)
      o[dg] = __builtin_amdgcn_mfma_f32_16x16x32_bf16(vld(dg, 1), pb1.v, o[dg], 0, 0, 0);
    __builtin_amdgcn_s_setprio(0);
    __syncthreads();
  }

  unsigned short* cp = ctx + (size_t)b * SEQ * EDIM + h * DHEAD + (size_t)(qrow0 + l15) * EDIM;
  const float inv = 1.f / ls;
  #pragma unroll
  for (int dg = 0; dg < 4; ++dg) {
    uint2 w;
    w.x = cvtpk(o[dg][0] * inv, o[dg][1] * inv);
    w.y = cvtpk(o[dg][2] * inv, o[dg][3] * inv);
    *(uint2*)(cp + dg * 16 + lg * 4) = w;
  }
}

// ---------------- residual + layernorm; TWO: sum a + a2 (split-K halves) ----------------
template<int TWO>
__global__ __launch_bounds__(256) void ln_add_kernel(
    const float* __restrict__ a, const float* __restrict__ a2,
    const float* __restrict__ g, const float* __restrict__ bb,
    float* __restrict__ x, unsigned short* __restrict__ xb) {
  const int row = blockIdx.x, t = threadIdx.x;
  float4 av = *(const float4*)(a + (size_t)row * EDIM + t * 4);
  if (TWO) {
    float4 a2v = *(const float4*)(a2 + (size_t)row * EDIM + t * 4);
    av.x += a2v.x; av.y += a2v.y; av.z += a2v.z; av.w += a2v.w;
  }
  float s = av.x + av.y + av.z + av.w;
  float qq = av.x * av.x + av.y * av.y + av.z * av.z + av.w * av.w;
  #pragma unroll
  for (int off = 1; off < 64; off <<= 1) { s += __shfl_xor(s, off); qq += __shfl_xor(qq, off); }
  __shared__ float red[8];
  const int wv = t >> 6;
  if ((t & 63) == 0) { red[wv] = s; red[4 + wv] = qq; }
  __syncthreads();
  s = red[0] + red[1] + red[2] + red[3];
  qq = red[4] + red[5] + red[6] + red[7];
  const float mean = s * (1.f / EDIM);
  const float rstd = rsqrtf(qq * (1.f / EDIM) - mean * mean + EPSF);
  float4 gv = *(const float4*)(g + t * 4);
  float4 bv = *(const float4*)(bb + t * 4);
  float* xr = x + (size_t)row * EDIM;
  float4 xv = *(float4*)(xr + t * 4);
  float4 o;
  o.x = xv.x + (av.x - mean) * rstd * gv.x + bv.x;
  o.y = xv.y + (av.y - mean) * rstd * gv.y + bv.y;
  o.z = xv.z + (av.z - mean) * rstd * gv.z + bv.z;
  o.w = xv.w + (av.w - mean) * rstd * gv.w + bv.w;
  *(float4*)(xr + t * 4) = o;
  unsigned short* xbr = xb + (size_t)row * EDIM + t * 4;
  xbr[0] = f2bf(o.x); xbr[1] = f2bf(o.y); xbr[2] = f2bf(o.z); xbr[3] = f2bf(o.w);
}

// ---------------- final double layernorm -> bf16 ----------------
__global__ __launch_bounds__(256) void final_ln_kernel(
    const float* __restrict__ x, const float* __restrict__ g1, const float* __restrict__ b1,
    const float* __restrict__ g2, const float* __restrict__ b2,
    unsigned short* __restrict__ xb) {
  const int row = blockIdx.x, t = threadIdx.x;
  __shared__ float red[8];
  const int wv = t >> 6;
  const float* xr = x + (size_t)row * EDIM;
  float4 v = *(const float4*)(xr + t * 4);

  float s = v.x + v.y + v.z + v.w;
  float qq = v.x * v.x + v.y * v.y + v.z * v.z + v.w * v.w;
  #pragma unroll
  for (int off = 1; off < 64; off <<= 1) { s += __shfl_xor(s, off); qq += __shfl_xor(qq, off); }
  if ((t & 63) == 0) { red[wv] = s; red[4 + wv] = qq; }
  __syncthreads();
  s = red[0] + red[1] + red[2] + red[3];
  qq = red[4] + red[5] + red[6] + red[7];
  __syncthreads();
  float mean = s * (1.f / EDIM);
  float rstd = rsqrtf(qq * (1.f / EDIM) - mean * mean + EPSF);
  float4 g1v = *(const float4*)(g1 + t * 4);
  float4 b1v = *(const float4*)(b1 + t * 4);
  float4 tv;
  tv.x = (v.x - mean) * rstd * g1v.x + b1v.x;
  tv.y = (v.y - mean) * rstd * g1v.y + b1v.y;
  tv.z = (v.z - mean) * rstd * g1v.z + b1v.z;
  tv.w = (v.w - mean) * rstd * g1v.w + b1v.w;

  s = tv.x + tv.y + tv.z + tv.w;
  qq = tv.x * tv.x + tv.y * tv.y + tv.z * tv.z + tv.w * tv.w;
  #pragma unroll
  for (int off = 1; off < 64; off <<= 1) { s += __shfl_xor(s, off); qq += __shfl_xor(qq, off); }
  if ((t & 63) == 0) { red[wv] = s; red[4 + wv] = qq; }
  __syncthreads();
  s = red[0] + red[1] + red[2] + red[3];
  qq = red[4] + red[5] + red[6] + red[7];
  mean = s * (1.f / EDIM);
  rstd = rsqrtf(qq * (1.f / EDIM) - mean * mean + EPSF);
  float4 g2v = *(const float4*)(g2 + t * 4);
  float4 b2v = *(const float4*)(b2 + t * 4);
  unsigned short* o = xb + (size_t)row * EDIM + t * 4;
  o[0] = f2bf((tv.x - mean) * rstd * g2v.x + b2v.x);
  o[1] = f2bf((tv.y - mean) * rstd * g2v.y + b2v.y);
  o[2] = f2bf((tv.z - mean) * rstd * g2v.z + b2v.z);
  o[3] = f2bf((tv.w - mean) * rstd * g2v.w + b2v.w);
}

// ---------------- launch ----------------
extern "C" void kernel_launch(void* const* d_in, const int* in_sizes, int n_in,
                              void* d_out, int out_size, void* d_ws, size_t ws_size,
                              hipStream_t stream) {
  const int*   tokens = (const int*)d_in[0];
  const float* emb    = (const float*)d_in[1];
  const float* pe     = (const float*)d_in[2];
  const float* Wq     = (const float*)d_in[3];
  const float* Wk     = (const float*)d_in[4];
  const float* Wv     = (const float*)d_in[5];
  const float* Wo     = (const float*)d_in[6];
  const float* W1     = (const float*)d_in[7];
  const float* W2     = (const float*)d_in[8];
  const float* bq     = (const float*)d_in[9];
  const float* bk     = (const float*)d_in[10];
  const float* bv     = (const float*)d_in[11];
  const float* bo     = (const float*)d_in[12];
  const float* b1     = (const float*)d_in[13];
  const float* b2     = (const float*)d_in[14];
  const float* ln1_g  = (const float*)d_in[15];
  const float* ln1_b  = (const float*)d_in[16];
  const float* ln2_g  = (const float*)d_in[17];
  const float* ln2_b  = (const float*)d_in[18];
  const float* enc_g  = (const float*)d_in[19];
  const float* enc_b  = (const float*)d_in[20];
  const float* fin_g  = (const float*)d_in[21];
  const float* fin_b  = (const float*)d_in[22];
  const float* Wout   = (const float*)d_in[23];
  const float* bout   = (const float*)d_in[24];
  float* out = (float*)d_out;

  uint8_t* p = (uint8_t*)d_ws;
  auto alloc = [&](size_t bytes) {
    void* r = (void*)p;
    p += (bytes + 255) & ~(size_t)255;
    return r;
  };
  float*          x     = (float*)alloc((size_t)MROWS * EDIM * 4);
  unsigned short* xb    = (unsigned short*)alloc((size_t)MROWS * EDIM * 2);
  float*          tbuf  = (float*)alloc((size_t)MROWS * EDIM * 4);
  unsigned short* qkv   = (unsigned short*)alloc((size_t)MROWS * QKVLD * 2);
  unsigned short* ctx   = (unsigned short*)alloc((size_t)MROWS * EDIM * 2);
  unsigned short* wlt   = (unsigned short*)alloc((size_t)NLAYER * 12 * 1024 * 1024 * 2);
  unsigned short* woutt = (unsigned short*)alloc((size_t)VOCAB * EDIM * 2);
  float*          bqkv  = (float*)alloc((size_t)NLAYER * QKVLD * 4);
  unsigned short* ff1   = qkv;  // alias: qkv+ctx dead when ff1 is live
  if ((size_t)(p - (uint8_t*)d_ws) > ws_size) return;
  float* tbuf2 = (float*)alloc((size_t)MROWS * EDIM * 4);
  const bool have2 = (size_t)(p - (uint8_t*)d_ws) <= ws_size;

  const dim3 blk(256);
  const size_t LW = (size_t)12 * 1024 * 1024;
  const size_t M1 = 1024 * 1024;

  transpose_w<<<dim3(16, 16, NLAYER), blk, 0, stream>>>(Wq, wlt,          1024, 1024, ALPHA, M1, LW);
  transpose_w<<<dim3(16, 16, NLAYER), blk, 0, stream>>>(Wk, wlt + M1,     1024, 1024, 1.0f,  M1, LW);
  transpose_w<<<dim3(16, 16, NLAYER), blk, 0, stream>>>(Wv, wlt + 2 * M1, 1024, 1024, 1.0f,  M1, LW);
  transpose_w<<<dim3(16, 16, NLAYER), blk, 0, stream>>>(Wo, wlt + 3 * M1, 1024, 1024, 1.0f,  M1, LW);
  transpose_w<<<dim3(16, 64, NLAYER), blk, 0, stream>>>(W1, wlt + 4 * M1, 4096, 1024, 1.0f, 4 * M1, LW);
  transpose_w<<<dim3(64, 16, NLAYER), blk, 0, stream>>>(W2, wlt + 8 * M1, 1024, 4096, 1.0f, 4 * M1, LW);
  transpose_w<<<dim3(16, 500), blk, 0, stream>>>(Wout, woutt, VOCAB, 1024, 1.0f, 0, 0);
  pack_bias<<<(NLAYER * QKVLD + 255) / 256, blk, 0, stream>>>(bq, bk, bv, bqkv);

  embed_kernel<<<MROWS, blk, 0, stream>>>(tokens, emb, pe, x, xb);

  const int MB1 = MROWS / 128;   // 32
  for (int i = 0; i < NLAYER; ++i) {
    unsigned short* lb = wlt + (size_t)i * LW;
    gemm3<128, 1, 0, 0><<<MB1 * (QKVLD / 128), blk, 0, stream>>>(
        xb, lb, bqkv + (size_t)i * QKVLD, qkv, nullptr, QKVLD, EDIM, EDIM, QKVLD / 128, 8);
    attn_kernel<<<dim3(SEQ / 64, NHEAD, BATCH), blk, 0, stream>>>(qkv, ctx);
    if (have2) {
      gemm3<128, 0, 0, 1><<<dim3(MB1 * (EDIM / 128), 2), blk, 0, stream>>>(
          ctx, lb + 3 * M1, bo + i * EDIM, tbuf, tbuf2, EDIM, EDIM / 2, EDIM, EDIM / 128, 8);
      ln_add_kernel<1><<<MROWS, blk, 0, stream>>>(tbuf, tbuf2, ln1_g + i * EDIM, ln1_b + i * EDIM, x, xb);
    } else {
      gemm3<128, 0, 0, 0><<<MB1 * (EDIM / 128), blk, 0, stream>>>(
          ctx, lb + 3 * M1, bo + i * EDIM, tbuf, nullptr, EDIM, EDIM, EDIM, EDIM / 128, 8);
      ln_add_kernel<0><<<MROWS, blk, 0, stream>>>(tbuf, nullptr, ln1_g + i * EDIM, ln1_b + i * EDIM, x, xb);
    }
    gemm3<128, 1, 1, 0><<<MB1 * (DFFDIM / 128), blk, 0, stream>>>(
        xb, lb + 4 * M1, b1 + i * DFFDIM, ff1, nullptr, DFFDIM, EDIM, EDIM, DFFDIM / 128, 8);
    if (have2) {
      gemm3<128, 0, 0, 1><<<dim3(MB1 * (EDIM / 128), 2), blk, 0, stream>>>(
          ff1, lb + 8 * M1, b2 + i * EDIM, tbuf, tbuf2, EDIM, DFFDIM / 2, DFFDIM, EDIM / 128, 8);
      ln_add_kernel<1><<<MROWS, blk, 0, stream>>>(tbuf, tbuf2, ln2_g + i * EDIM, ln2_b + i * EDIM, x, xb);
    } else {
      gemm3<128, 0, 0, 0><<<MB1 * (EDIM / 128), blk, 0, stream>>>(
          ff1, lb + 8 * M1, b2 + i * EDIM, tbuf, nullptr, EDIM, DFFDIM, DFFDIM, EDIM / 128, 8);
      ln_add_kernel<0><<<MROWS, blk, 0, stream>>>(tbuf, nullptr, ln2_g + i * EDIM, ln2_b + i * EDIM, x, xb);
    }
  }

  final_ln_kernel<<<MROWS, blk, 0, stream>>>(x, enc_g, enc_b, fin_g, fin_b, xb);
  // vocab GEMM at 128^2: 8000 blocks, 3 blocks/CU (TLP across independent barrier groups), G=10
  gemm3<128, 0, 0, 0><<<MB1 * (VOCAB / 128), blk, 0, stream>>>(
      xb, woutt, bout, out, nullptr, VOCAB, EDIM, EDIM, VOCAB / 128, 10);
}

// Round 17
// 1291.723 us; speedup vs baseline: 1.0375x; 1.0375x over previous
//
#include <hip/hip_runtime.h>
#include <hip/hip_bf16.h>
#include <stdint.h>

#define EDIM 1024
#define DFFDIM 4096
#define NLAYER 4
#define BATCH 4
#define SEQ 1024
#define NHEAD 16
#define DHEAD 64
#define VOCAB 32000
#define MROWS (BATCH*SEQ)
#define QKVLD (3*EDIM)
#define EPSF 1e-6f
#define ALPHA 0.18033688011112043f   // 0.125 * log2(e): folded into Wq/bq

typedef float f32x4 __attribute__((ext_vector_type(4)));
typedef short s16x8 __attribute__((ext_vector_type(8)));
typedef __bf16 bf16x8 __attribute__((ext_vector_type(8)));

__device__ inline unsigned short f2bf(float f) {
  union { float f; uint32_t u; } v; v.f = f;
  uint32_t r = v.u + 0x7fffu + ((v.u >> 16) & 1u);
  return (unsigned short)(r >> 16);
}

__device__ __forceinline__ float fexp2(float x) {
  float r; asm("v_exp_f32 %0, %1" : "=v"(r) : "v"(x)); return r;
}
__device__ __forceinline__ uint32_t cvtpk(float lo, float hi) {
  uint32_t r; asm("v_cvt_pk_bf16_f32 %0, %1, %2" : "=v"(r) : "v"(lo), "v"(hi)); return r;
}

__device__ __forceinline__ void gload16(const void* g, void* l) {
  __builtin_amdgcn_global_load_lds(
      (const __attribute__((address_space(1))) void*)g,
      (__attribute__((address_space(3))) void*)l, 16, 0, 0);
}

// ---------------- embedding + positional encoding ----------------
__global__ __launch_bounds__(256) void embed_kernel(
    const int* __restrict__ tokens, const float* __restrict__ emb,
    const float* __restrict__ pe, float* __restrict__ x,
    unsigned short* __restrict__ xb) {
  const int row = blockIdx.x;
  const int s = row & (SEQ - 1);
  const int tok = tokens[row];
  const int c = threadIdx.x * 4;
  float4 ev = *(const float4*)(emb + (size_t)tok * EDIM + c);
  float4 pv = *(const float4*)(pe + (size_t)s * EDIM + c);
  float4 o;
  o.x = ev.x + pv.x; o.y = ev.y + pv.y; o.z = ev.z + pv.z; o.w = ev.w + pv.w;
  *(float4*)(x + (size_t)row * EDIM + c) = o;
  unsigned short* xr = xb + (size_t)row * EDIM + c;
  xr[0] = f2bf(o.x); xr[1] = f2bf(o.y); xr[2] = f2bf(o.z); xr[3] = f2bf(o.w);
}

// ---------------- weight transpose+convert, layer-batched via blockIdx.z ----------------
__global__ __launch_bounds__(256) void transpose_w(
    const float* __restrict__ src0, unsigned short* __restrict__ dst0,
    int N, int K, float scale, size_t srcStride, size_t dstStride) {
  const float* src = src0 + (size_t)blockIdx.z * srcStride;
  unsigned short* dst = dst0 + (size_t)blockIdx.z * dstStride;
  __shared__ float tl[64][65];
  const int t = threadIdx.x;
  const int k0 = blockIdx.x * 64, n0 = blockIdx.y * 64;
  const int c = (t & 15) * 4, r0 = t >> 4;
  #pragma unroll
  for (int i = 0; i < 4; ++i) {
    const int r = r0 + i * 16;
    float4 v = *(const float4*)(src + (size_t)(k0 + r) * N + n0 + c);
    tl[r][c] = v.x; tl[r][c + 1] = v.y; tl[r][c + 2] = v.z; tl[r][c + 3] = v.w;
  }
  __syncthreads();
  #pragma unroll
  for (int i = 0; i < 4; ++i) {
    const int n = r0 + i * 16;
    uint2 o;
    o.x = (uint32_t)f2bf(tl[c + 0][n] * scale) | ((uint32_t)f2bf(tl[c + 1][n] * scale) << 16);
    o.y = (uint32_t)f2bf(tl[c + 2][n] * scale) | ((uint32_t)f2bf(tl[c + 3][n] * scale) << 16);
    *(uint2*)(dst + (size_t)(n0 + n) * K + k0 + c) = o;
  }
}

// ---------------- pack qkv bias (bq scaled by ALPHA) ----------------
__global__ __launch_bounds__(256) void pack_bias(
    const float* __restrict__ bq, const float* __restrict__ bk,
    const float* __restrict__ bv, float* __restrict__ dst) {
  const int idx = blockIdx.x * 256 + threadIdx.x;
  if (idx >= NLAYER * QKVLD) return;
  const int layer = idx / QKVLD, c = idx % QKVLD;
  float v;
  if (c < 1024)      v = bq[layer * 1024 + c] * ALPHA;
  else if (c < 2048) v = bk[layer * 1024 + c - 1024];
  else               v = bv[layer * 1024 + c - 2048];
  dst[idx] = v;
}

// ---------------- 3-deep pipelined GEMM, BK=32, counted vmcnt, supergrouped tiles ----------------
template<int BM, int OUT_BF16, int RELU, int SPLITK>
__global__ __launch_bounds__(BM * 2, (BM == 256) ? 2 : 3) void gemm3(
    const unsigned short* __restrict__ A, const unsigned short* __restrict__ Bt,
    const float* __restrict__ bias, void* __restrict__ Cout, void* __restrict__ C2,
    int Nld, int KLEN, int KLD, int NBLK, int G) {
  constexpr int BUFB = BM * 128;
  constexpr int ABYTES = BM * 64;
  constexpr int WN = (BM == 256) ? 4 : 2;
  constexpr int MF = BM / 32;
  __shared__ __attribute__((aligned(16))) char smb[3 * BUFB];
  const int t = threadIdx.x, lane = t & 63;
  const int wave = t >> 6;
  const int wr = wave / WN, wc = wave % WN;
  const int l15 = lane & 15, lg = lane >> 4;

  const int cpx = gridDim.x >> 3;
  const int bid = blockIdx.x;
  const int swz = (bid & 7) * cpx + (bid >> 3);
  const int sg = (gridDim.x / NBLK) * G;
  const int ns = swz / sg, rem = swz % sg;
  const int m0 = (rem / G) * BM;
  const int n0 = (ns * G + rem % G) * BM;
  const int koff = SPLITK ? blockIdx.y * KLEN : 0;

  f32x4 acc[MF][4];
  #pragma unroll
  for (int i = 0; i < MF; ++i)
    #pragma unroll
    for (int j = 0; j < 4; ++j)
      acc[i][j] = (f32x4){0.f, 0.f, 0.f, 0.f};

  const int srow = t >> 2;
  const int scol = (((t & 3) ^ ((t >> 3) & 3)) << 3);
  const unsigned short* agp = A  + (size_t)(m0 + srow) * KLD + scol + koff;
  const unsigned short* bgp = Bt + (size_t)(n0 + srow) * KLD + scol + koff;
  const size_t rhalf = (size_t)(BM / 2) * KLD;

  const int cxo = (lg * 16) ^ (((l15 >> 1) & 3) << 4);
  const int rdA = (wr * (BM / 2) + l15) * 64 + cxo;
  const int rdB = ABYTES + (wc * 64 + l15) * 64 + cxo;

  auto stage_tile = [&](int b, int kt) {
    const int k0 = kt * 32;
    char* d = smb + b * BUFB + t * 16;
    gload16(agp + k0, d);
    gload16(agp + rhalf + k0, d + BM * 32);
    gload16(bgp + k0, d + ABYTES);
    gload16(bgp + rhalf + k0, d + ABYTES + BM * 32);
  };

  const int NT = KLEN / 32;
  stage_tile(0, 0);
  stage_tile(1, 1);
  asm volatile("s_waitcnt vmcnt(4)" ::: "memory");
  __builtin_amdgcn_s_barrier();
  __builtin_amdgcn_sched_barrier(0);

  int bufc = 0, bufn = 2;
  for (int tt = 0; tt < NT; ++tt) {
    if (tt + 2 < NT) stage_tile(bufn, tt + 2);

    const char* ab = smb + bufc * BUFB;
    bf16x8 af[MF], bf[4];
    #pragma unroll
    for (int mf = 0; mf < MF; ++mf)
      af[mf] = *(const bf16x8*)(ab + rdA + mf * 1024);
    #pragma unroll
    for (int nf = 0; nf < 4; ++nf)
      bf[nf] = *(const bf16x8*)(ab + rdB + nf * 1024);

    __builtin_amdgcn_s_setprio(1);
    #pragma unroll
    for (int mf = 0; mf < MF; ++mf)
      #pragma unroll
      for (int nf = 0; nf < 4; ++nf)
        acc[mf][nf] = __builtin_amdgcn_mfma_f32_16x16x32_bf16(af[mf], bf[nf], acc[mf][nf], 0, 0, 0);
    __builtin_amdgcn_s_setprio(0);

    if (tt + 2 < NT)      asm volatile("s_waitcnt vmcnt(4)" ::: "memory");
    else if (tt + 1 < NT) asm volatile("s_waitcnt vmcnt(0)" ::: "memory");
    __builtin_amdgcn_sched_barrier(0);
    __builtin_amdgcn_s_barrier();
    __builtin_amdgcn_sched_barrier(0);

    bufc = (bufc == 2) ? 0 : bufc + 1;
    bufn = (bufn == 2) ? 0 : bufn + 1;
  }

  void* Cw = (SPLITK && blockIdx.y) ? C2 : Cout;
  #pragma unroll
  for (int mf = 0; mf < MF; ++mf) {
    #pragma unroll
    for (int nf = 0; nf < 4; ++nf) {
      const int col = n0 + wc * 64 + nf * 16 + l15;
      const float bv = (SPLITK && blockIdx.y) ? 0.f : bias[col];
      #pragma unroll
      for (int r = 0; r < 4; ++r) {
        const int row = m0 + wr * (BM / 2) + mf * 16 + lg * 4 + r;
        float val = acc[mf][nf][r] + bv;
        if (RELU) val = fmaxf(val, 0.f);
        if (OUT_BF16)
          ((unsigned short*)Cw)[(size_t)row * Nld + col] = f2bf(val);
        else
          ((float*)Cw)[(size_t)row * Nld + col] = val;
      }
    }
  }
}

// ---------------- flash attention: swapped QK^T, 32 q-rows/wave, in-lane softmax ----------------
// Each wave owns q-halves A (qBase..+15) and B (qBase+16..+31); K/V LDS reads + staging
// + barriers are shared across both halves (all shared costs halve per q).
__global__ __launch_bounds__(256) void attn_kernel(
    const unsigned short* __restrict__ qkv, unsigned short* __restrict__ ctx) {
  const int b = blockIdx.z, h = blockIdx.y;
  const int t = threadIdx.x, wave = t >> 6, lane = t & 63;
  const int l15 = lane & 15, lg = lane >> 4;
  const int qBase = blockIdx.x * 128 + wave * 32;
  const unsigned short* qbs = qkv + (size_t)b * SEQ * QKVLD + h * DHEAD;
  const unsigned short* kbs = qbs + EDIM;
  const unsigned short* vbs = qbs + 2 * EDIM;
  __shared__ unsigned short Ksm[64][72];
  __shared__ unsigned short VTs[64 * 64];

  const unsigned short* qpA = qbs + (size_t)(qBase + l15) * QKVLD + lg * 8;
  const unsigned short* qpB = qbs + (size_t)(qBase + 16 + l15) * QKVLD + lg * 8;
  bf16x8 aA0 = *(const bf16x8*)qpA;
  bf16x8 aA1 = *(const bf16x8*)(qpA + 32);
  bf16x8 aB0 = *(const bf16x8*)qpB;
  bf16x8 aB1 = *(const bf16x8*)(qpB + 32);

  f32x4 oA[4], oB[4];
  #pragma unroll
  for (int dg = 0; dg < 4; ++dg) { oA[dg] = (f32x4){0,0,0,0}; oB[dg] = (f32x4){0,0,0,0}; }
  float mA = -1e30f, lsA = 0.f, mB = -1e30f, lsB = 0.f;

  const int sr = t >> 2;
  const int sc = (t & 3) * 16;
  const int posw = (((sr >> 4) & 1) << 5) | (((sr & 15) >> 2) << 3) | (((sr >> 5) & 1) << 2) | (sr & 3);
  const unsigned short* kgp = kbs + (size_t)sr * QKVLD + sc;
  const unsigned short* vgp = vbs + (size_t)sr * QKVLD + sc;
  const size_t tilestep = (size_t)64 * QKVLD;

  s16x8 kr0 = *(const s16x8*)kgp, kr1 = *(const s16x8*)(kgp + 8);
  s16x8 vr0 = *(const s16x8*)vgp, vr1 = *(const s16x8*)(vgp + 8);

  const int NT = SEQ / 64;
  for (int j = 0; j < NT; ++j) {
    *(s16x8*)&Ksm[sr][sc] = kr0;
    *(s16x8*)&Ksm[sr][sc + 8] = kr1;
    #pragma unroll
    for (int c = 0; c < 2; ++c) {
      s16x8 vv = c ? vr1 : vr0;
      #pragma unroll
      for (int e = 0; e < 8; ++e) {
        const int d = sc + c * 8 + e;
        const int byteo = d * 128 + ((posw * 2) ^ ((d & 7) << 4));
        *(unsigned short*)((char*)VTs + byteo) = (unsigned short)vv[e];
      }
    }
    __syncthreads();

    // swapped QK^T for both q-halves; K fragments loaded once
    f32x4 sA[4], sB[4];
    __builtin_amdgcn_s_setprio(1);
    #pragma unroll
    for (int g = 0; g < 4; ++g) {
      bf16x8 k0 = *(const bf16x8*)&Ksm[g * 16 + l15][lg * 8];
      bf16x8 k1 = *(const bf16x8*)&Ksm[g * 16 + l15][32 + lg * 8];
      f32x4 zA = {0,0,0,0}, zB = {0,0,0,0};
      zA = __builtin_amdgcn_mfma_f32_16x16x32_bf16(k0, aA0, zA, 0, 0, 0);
      sA[g] = __builtin_amdgcn_mfma_f32_16x16x32_bf16(k1, aA1, zA, 0, 0, 0);
      zB = __builtin_amdgcn_mfma_f32_16x16x32_bf16(k0, aB0, zB, 0, 0, 0);
      sB[g] = __builtin_amdgcn_mfma_f32_16x16x32_bf16(k1, aB1, zB, 0, 0, 0);
    }
    __builtin_amdgcn_s_setprio(0);

    if (j + 1 < NT) {   // T14 reg prefetch
      const unsigned short* kn = kgp + (size_t)(j + 1) * tilestep;
      const unsigned short* vn = vgp + (size_t)(j + 1) * tilestep;
      kr0 = *(const s16x8*)kn; kr1 = *(const s16x8*)(kn + 8);
      vr0 = *(const s16x8*)vn; vr1 = *(const s16x8*)(vn + 8);
    }

    float mxA = sA[0][0], mxB = sB[0][0];
    #pragma unroll
    for (int g = 0; g < 4; ++g)
      #pragma unroll
      for (int r = 0; r < 4; ++r) { mxA = fmaxf(mxA, sA[g][r]); mxB = fmaxf(mxB, sB[g][r]); }
    mxA = fmaxf(mxA, __shfl_xor(mxA, 16)); mxA = fmaxf(mxA, __shfl_xor(mxA, 32));
    mxB = fmaxf(mxB, __shfl_xor(mxB, 16)); mxB = fmaxf(mxB, __shfl_xor(mxB, 32));

    if (__any((mxA > mA + 8.f) || (mxB > mB + 8.f))) {
      const float mnA = fmaxf(mA, mxA), mnB = fmaxf(mB, mxB);
      const float sclA = fexp2(mA - mnA), sclB = fexp2(mB - mnB);
      mA = mnA; mB = mnB;
      lsA *= sclA; lsB *= sclB;
      #pragma unroll
      for (int dg = 0; dg < 4; ++dg)
        #pragma unroll
        for (int r = 0; r < 4; ++r) { oA[dg][r] *= sclA; oB[dg][r] *= sclB; }
    }
    #pragma unroll
    for (int g = 0; g < 4; ++g)
      #pragma unroll
      for (int r = 0; r < 4; ++r) { sA[g][r] = fexp2(sA[g][r] - mA); sB[g][r] = fexp2(sB[g][r] - mB); }

    float rsA = 0.f, rsB = 0.f;
    #pragma unroll
    for (int g = 0; g < 4; ++g) {
      rsA += (sA[g][0] + sA[g][1]) + (sA[g][2] + sA[g][3]);
      rsB += (sB[g][0] + sB[g][1]) + (sB[g][2] + sB[g][3]);
    }
    rsA += __shfl_xor(rsA, 16); rsA += __shfl_xor(rsA, 32);
    rsB += __shfl_xor(rsB, 16); rsB += __shfl_xor(rsB, 32);
    lsA += rsA; lsB += rsB;

    union { uint32_t u[4]; bf16x8 v; } pA0, pA1, pB0, pB1;
    pA0.u[0] = cvtpk(sA[0][0], sA[0][1]); pA0.u[1] = cvtpk(sA[0][2], sA[0][3]);
    pA0.u[2] = cvtpk(sA[2][0], sA[2][1]); pA0.u[3] = cvtpk(sA[2][2], sA[2][3]);
    pA1.u[0] = cvtpk(sA[1][0], sA[1][1]); pA1.u[1] = cvtpk(sA[1][2], sA[1][3]);
    pA1.u[2] = cvtpk(sA[3][0], sA[3][1]); pA1.u[3] = cvtpk(sA[3][2], sA[3][3]);
    pB0.u[0] = cvtpk(sB[0][0], sB[0][1]); pB0.u[1] = cvtpk(sB[0][2], sB[0][3]);
    pB0.u[2] = cvtpk(sB[2][0], sB[2][1]); pB0.u[3] = cvtpk(sB[2][2], sB[2][3]);
    pB1.u[0] = cvtpk(sB[1][0], sB[1][1]); pB1.u[1] = cvtpk(sB[1][2], sB[1][3]);
    pB1.u[2] = cvtpk(sB[3][0], sB[3][1]); pB1.u[3] = cvtpk(sB[3][2], sB[3][3]);

    auto vld = [&](int dg, int c) {
      const int byteo = (dg * 16 + l15) * 128 + ((c * 64 + lg * 16) ^ ((l15 & 7) << 4));
      return *(const bf16x8*)((const char*)VTs + byteo);
    };
    __builtin_amdgcn_s_setprio(1);
    #pragma unroll
    for (int dg = 0; dg < 4; ++dg) {
      bf16x8 v0 = vld(dg, 0);   // shared V fragment serves both halves
      oA[dg] = __builtin_amdgcn_mfma_f32_16x16x32_bf16(v0, pA0.v, oA[dg], 0, 0, 0);
      oB[dg] = __builtin_amdgcn_mfma_f32_16x16x32_bf16(v0, pB0.v, oB[dg], 0, 0, 0);
    }
    #pragma unroll
    for (int dg = 0; dg < 4; ++dg) {
      bf16x8 v1 = vld(dg, 1);
      oA[dg] = __builtin_amdgcn_mfma_f32_16x16x32_bf16(v1, pA1.v, oA[dg], 0, 0, 0);
      oB[dg] = __builtin_amdgcn_mfma_f32_16x16x32_bf16(v1, pB1.v, oB[dg], 0, 0, 0);
    }
    __builtin_amdgcn_s_setprio(0);
    __syncthreads();
  }

  unsigned short* base = ctx + (size_t)b * SEQ * EDIM + h * DHEAD;
  unsigned short* cpA = base + (size_t)(qBase + l15) * EDIM;
  unsigned short* cpB = base + (size_t)(qBase + 16 + l15) * EDIM;
  const float invA = 1.f / lsA, invB = 1.f / lsB;
  #pragma unroll
  for (int dg = 0; dg < 4; ++dg) {
    uint2 wA, wB;
    wA.x = cvtpk(oA[dg][0] * invA, oA[dg][1] * invA);
    wA.y = cvtpk(oA[dg][2] * invA, oA[dg][3] * invA);
    wB.x = cvtpk(oB[dg][0] * invB, oB[dg][1] * invB);
    wB.y = cvtpk(oB[dg][2] * invB, oB[dg][3] * invB);
    *(uint2*)(cpA + dg * 16 + lg * 4) = wA;
    *(uint2*)(cpB + dg * 16 + lg * 4) = wB;
  }
}

// ---------------- residual + layernorm; TWO: sum a + a2 (split-K halves) ----------------
template<int TWO>
__global__ __launch_bounds__(256) void ln_add_kernel(
    const float* __restrict__ a, const float* __restrict__ a2,
    const float* __restrict__ g, const float* __restrict__ bb,
    float* __restrict__ x, unsigned short* __restrict__ xb) {
  const int row = blockIdx.x, t = threadIdx.x;
  float4 av = *(const float4*)(a + (size_t)row * EDIM + t * 4);
  if (TWO) {
    float4 a2v = *(const float4*)(a2 + (size_t)row * EDIM + t * 4);
    av.x += a2v.x; av.y += a2v.y; av.z += a2v.z; av.w += a2v.w;
  }
  float s = av.x + av.y + av.z + av.w;
  float qq = av.x * av.x + av.y * av.y + av.z * av.z + av.w * av.w;
  #pragma unroll
  for (int off = 1; off < 64; off <<= 1) { s += __shfl_xor(s, off); qq += __shfl_xor(qq, off); }
  __shared__ float red[8];
  const int wv = t >> 6;
  if ((t & 63) == 0) { red[wv] = s; red[4 + wv] = qq; }
  __syncthreads();
  s = red[0] + red[1] + red[2] + red[3];
  qq = red[4] + red[5] + red[6] + red[7];
  const float mean = s * (1.f / EDIM);
  const float rstd = rsqrtf(qq * (1.f / EDIM) - mean * mean + EPSF);
  float4 gv = *(const float4*)(g + t * 4);
  float4 bv = *(const float4*)(bb + t * 4);
  float* xr = x + (size_t)row * EDIM;
  float4 xv = *(float4*)(xr + t * 4);
  float4 o;
  o.x = xv.x + (av.x - mean) * rstd * gv.x + bv.x;
  o.y = xv.y + (av.y - mean) * rstd * gv.y + bv.y;
  o.z = xv.z + (av.z - mean) * rstd * gv.z + bv.z;
  o.w = xv.w + (av.w - mean) * rstd * gv.w + bv.w;
  *(float4*)(xr + t * 4) = o;
  unsigned short* xbr = xb + (size_t)row * EDIM + t * 4;
  xbr[0] = f2bf(o.x); xbr[1] = f2bf(o.y); xbr[2] = f2bf(o.z); xbr[3] = f2bf(o.w);
}

// ---------------- final double layernorm -> bf16 ----------------
__global__ __launch_bounds__(256) void final_ln_kernel(
    const float* __restrict__ x, const float* __restrict__ g1, const float* __restrict__ b1,
    const float* __restrict__ g2, const float* __restrict__ b2,
    unsigned short* __restrict__ xb) {
  const int row = blockIdx.x, t = threadIdx.x;
  __shared__ float red[8];
  const int wv = t >> 6;
  const float* xr = x + (size_t)row * EDIM;
  float4 v = *(const float4*)(xr + t * 4);

  float s = v.x + v.y + v.z + v.w;
  float qq = v.x * v.x + v.y * v.y + v.z * v.z + v.w * v.w;
  #pragma unroll
  for (int off = 1; off < 64; off <<= 1) { s += __shfl_xor(s, off); qq += __shfl_xor(qq, off); }
  if ((t & 63) == 0) { red[wv] = s; red[4 + wv] = qq; }
  __syncthreads();
  s = red[0] + red[1] + red[2] + red[3];
  qq = red[4] + red[5] + red[6] + red[7];
  __syncthreads();
  float mean = s * (1.f / EDIM);
  float rstd = rsqrtf(qq * (1.f / EDIM) - mean * mean + EPSF);
  float4 g1v = *(const float4*)(g1 + t * 4);
  float4 b1v = *(const float4*)(b1 + t * 4);
  float4 tv;
  tv.x = (v.x - mean) * rstd * g1v.x + b1v.x;
  tv.y = (v.y - mean) * rstd * g1v.y + b1v.y;
  tv.z = (v.z - mean) * rstd * g1v.z + b1v.z;
  tv.w = (v.w - mean) * rstd * g1v.w + b1v.w;

  s = tv.x + tv.y + tv.z + tv.w;
  qq = tv.x * tv.x + tv.y * tv.y + tv.z * tv.z + tv.w * tv.w;
  #pragma unroll
  for (int off = 1; off < 64; off <<= 1) { s += __shfl_xor(s, off); qq += __shfl_xor(qq, off); }
  if ((t & 63) == 0) { red[wv] = s; red[4 + wv] = qq; }
  __syncthreads();
  s = red[0] + red[1] + red[2] + red[3];
  qq = red[4] + red[5] + red[6] + red[7];
  mean = s * (1.f / EDIM);
  rstd = rsqrtf(qq * (1.f / EDIM) - mean * mean + EPSF);
  float4 g2v = *(const float4*)(g2 + t * 4);
  float4 b2v = *(const float4*)(b2 + t * 4);
  unsigned short* o = xb + (size_t)row * EDIM + t * 4;
  o[0] = f2bf((tv.x - mean) * rstd * g2v.x + b2v.x);
  o[1] = f2bf((tv.y - mean) * rstd * g2v.y + b2v.y);
  o[2] = f2bf((tv.z - mean) * rstd * g2v.z + b2v.z);
  o[3] = f2bf((tv.w - mean) * rstd * g2v.w + b2v.w);
}

// ---------------- launch ----------------
extern "C" void kernel_launch(void* const* d_in, const int* in_sizes, int n_in,
                              void* d_out, int out_size, void* d_ws, size_t ws_size,
                              hipStream_t stream) {
  const int*   tokens = (const int*)d_in[0];
  const float* emb    = (const float*)d_in[1];
  const float* pe     = (const float*)d_in[2];
  const float* Wq     = (const float*)d_in[3];
  const float* Wk     = (const float*)d_in[4];
  const float* Wv     = (const float*)d_in[5];
  const float* Wo     = (const float*)d_in[6];
  const float* W1     = (const float*)d_in[7];
  const float* W2     = (const float*)d_in[8];
  const float* bq     = (const float*)d_in[9];
  const float* bk     = (const float*)d_in[10];
  const float* bv     = (const float*)d_in[11];
  const float* bo     = (const float*)d_in[12];
  const float* b1     = (const float*)d_in[13];
  const float* b2     = (const float*)d_in[14];
  const float* ln1_g  = (const float*)d_in[15];
  const float* ln1_b  = (const float*)d_in[16];
  const float* ln2_g  = (const float*)d_in[17];
  const float* ln2_b  = (const float*)d_in[18];
  const float* enc_g  = (const float*)d_in[19];
  const float* enc_b  = (const float*)d_in[20];
  const float* fin_g  = (const float*)d_in[21];
  const float* fin_b  = (const float*)d_in[22];
  const float* Wout   = (const float*)d_in[23];
  const float* bout   = (const float*)d_in[24];
  float* out = (float*)d_out;

  uint8_t* p = (uint8_t*)d_ws;
  auto alloc = [&](size_t bytes) {
    void* r = (void*)p;
    p += (bytes + 255) & ~(size_t)255;
    return r;
  };
  float*          x     = (float*)alloc((size_t)MROWS * EDIM * 4);
  unsigned short* xb    = (unsigned short*)alloc((size_t)MROWS * EDIM * 2);
  float*          tbuf  = (float*)alloc((size_t)MROWS * EDIM * 4);
  unsigned short* qkv   = (unsigned short*)alloc((size_t)MROWS * QKVLD * 2);
  unsigned short* ctx   = (unsigned short*)alloc((size_t)MROWS * EDIM * 2);
  unsigned short* wlt   = (unsigned short*)alloc((size_t)NLAYER * 12 * 1024 * 1024 * 2);
  unsigned short* woutt = (unsigned short*)alloc((size_t)VOCAB * EDIM * 2);
  float*          bqkv  = (float*)alloc((size_t)NLAYER * QKVLD * 4);
  unsigned short* ff1   = qkv;  // alias: qkv+ctx dead when ff1 is live
  if ((size_t)(p - (uint8_t*)d_ws) > ws_size) return;
  float* tbuf2 = (float*)alloc((size_t)MROWS * EDIM * 4);
  const bool have2 = (size_t)(p - (uint8_t*)d_ws) <= ws_size;

  const dim3 blk(256);
  const dim3 blk512(512);
  const size_t LW = (size_t)12 * 1024 * 1024;
  const size_t M1 = 1024 * 1024;

  transpose_w<<<dim3(16, 16, NLAYER), blk, 0, stream>>>(Wq, wlt,          1024, 1024, ALPHA, M1, LW);
  transpose_w<<<dim3(16, 16, NLAYER), blk, 0, stream>>>(Wk, wlt + M1,     1024, 1024, 1.0f,  M1, LW);
  transpose_w<<<dim3(16, 16, NLAYER), blk, 0, stream>>>(Wv, wlt + 2 * M1, 1024, 1024, 1.0f,  M1, LW);
  transpose_w<<<dim3(16, 16, NLAYER), blk, 0, stream>>>(Wo, wlt + 3 * M1, 1024, 1024, 1.0f,  M1, LW);
  transpose_w<<<dim3(16, 64, NLAYER), blk, 0, stream>>>(W1, wlt + 4 * M1, 4096, 1024, 1.0f, 4 * M1, LW);
  transpose_w<<<dim3(64, 16, NLAYER), blk, 0, stream>>>(W2, wlt + 8 * M1, 1024, 4096, 1.0f, 4 * M1, LW);
  transpose_w<<<dim3(16, 500), blk, 0, stream>>>(Wout, woutt, VOCAB, 1024, 1.0f, 0, 0);
  pack_bias<<<(NLAYER * QKVLD + 255) / 256, blk, 0, stream>>>(bq, bk, bv, bqkv);

  embed_kernel<<<MROWS, blk, 0, stream>>>(tokens, emb, pe, x, xb);

  const int MB2 = MROWS / 256;   // 16
  const int MB1 = MROWS / 128;   // 32
  for (int i = 0; i < NLAYER; ++i) {
    unsigned short* lb = wlt + (size_t)i * LW;
    gemm3<128, 1, 0, 0><<<MB1 * (QKVLD / 128), blk, 0, stream>>>(
        xb, lb, bqkv + (size_t)i * QKVLD, qkv, nullptr, QKVLD, EDIM, EDIM, QKVLD / 128, 8);
    attn_kernel<<<dim3(SEQ / 128, NHEAD, BATCH), blk, 0, stream>>>(qkv, ctx);
    if (have2) {
      gemm3<128, 0, 0, 1><<<dim3(MB1 * (EDIM / 128), 2), blk, 0, stream>>>(
          ctx, lb + 3 * M1, bo + i * EDIM, tbuf, tbuf2, EDIM, EDIM / 2, EDIM, EDIM / 128, 8);
      ln_add_kernel<1><<<MROWS, blk, 0, stream>>>(tbuf, tbuf2, ln1_g + i * EDIM, ln1_b + i * EDIM, x, xb);
    } else {
      gemm3<128, 0, 0, 0><<<MB1 * (EDIM / 128), blk, 0, stream>>>(
          ctx, lb + 3 * M1, bo + i * EDIM, tbuf, nullptr, EDIM, EDIM, EDIM, EDIM / 128, 8);
      ln_add_kernel<0><<<MROWS, blk, 0, stream>>>(tbuf, nullptr, ln1_g + i * EDIM, ln1_b + i * EDIM, x, xb);
    }
    gemm3<128, 1, 1, 0><<<MB1 * (DFFDIM / 128), blk, 0, stream>>>(
        xb, lb + 4 * M1, b1 + i * DFFDIM, ff1, nullptr, DFFDIM, EDIM, EDIM, DFFDIM / 128, 8);
    if (have2) {
      gemm3<128, 0, 0, 1><<<dim3(MB1 * (EDIM / 128), 2), blk, 0, stream>>>(
          ff1, lb + 8 * M1, b2 + i * EDIM, tbuf, tbuf2, EDIM, DFFDIM / 2, DFFDIM, EDIM / 128, 8);
      ln_add_kernel<1><<<MROWS, blk, 0, stream>>>(tbuf, tbuf2, ln2_g + i * EDIM, ln2_b + i * EDIM, x, xb);
    } else {
      gemm3<128, 0, 0, 0><<<MB1 * (EDIM / 128), blk, 0, stream>>>(
          ff1, lb + 8 * M1, b2 + i * EDIM, tbuf, nullptr, EDIM, DFFDIM, DFFDIM, EDIM / 128, 8);
      ln_add_kernel<0><<<MROWS, blk, 0, stream>>>(tbuf, nullptr, ln2_g + i * EDIM, ln2_b + i * EDIM, x, xb);
    }
  }

  final_ln_kernel<<<MROWS, blk, 0, stream>>>(x, enc_g, enc_b, fin_g, fin_b, xb);
  // vocab GEMM: 256^2, G=5 (best measured: 312 us, MfmaUtil 36.5%, FETCH 257MB)
  gemm3<256, 0, 0, 0><<<MB2 * (VOCAB / 256), blk512, 0, stream>>>(
      xb, woutt, bout, out, nullptr, VOCAB, EDIM, EDIM, VOCAB / 256, 5);
}

// Round 18
// 1264.711 us; speedup vs baseline: 1.0597x; 1.0214x over previous
//
#include <hip/hip_runtime.h>
#include <hip/hip_bf16.h>
#include <stdint.h>

#define EDIM 1024
#define DFFDIM 4096
#define NLAYER 4
#define BATCH 4
#define SEQ 1024
#define NHEAD 16
#define DHEAD 64
#define VOCAB 32000
#define MROWS (BATCH*SEQ)
#define QKVLD (3*EDIM)
#define EPSF 1e-6f
#define ALPHA 0.18033688011112043f   // 0.125 * log2(e): folded into Wq/bq

typedef float f32x4 __attribute__((ext_vector_type(4)));
typedef short s16x8 __attribute__((ext_vector_type(8)));
typedef __bf16 bf16x8 __attribute__((ext_vector_type(8)));

__device__ inline unsigned short f2bf(float f) {
  union { float f; uint32_t u; } v; v.f = f;
  uint32_t r = v.u + 0x7fffu + ((v.u >> 16) & 1u);
  return (unsigned short)(r >> 16);
}
__device__ __forceinline__ float b2f(unsigned short u) {
  union { uint32_t u; float f; } v; v.u = (uint32_t)u << 16; return v.f;
}

__device__ __forceinline__ float fexp2(float x) {
  float r; asm("v_exp_f32 %0, %1" : "=v"(r) : "v"(x)); return r;
}
__device__ __forceinline__ uint32_t cvtpk(float lo, float hi) {
  uint32_t r; asm("v_cvt_pk_bf16_f32 %0, %1, %2" : "=v"(r) : "v"(lo), "v"(hi)); return r;
}

__device__ __forceinline__ void gload16(const void* g, void* l) {
  __builtin_amdgcn_global_load_lds(
      (const __attribute__((address_space(1))) void*)g,
      (__attribute__((address_space(3))) void*)l, 16, 0, 0);
}

// ---------------- embedding + positional encoding ----------------
__global__ __launch_bounds__(256) void embed_kernel(
    const int* __restrict__ tokens, const float* __restrict__ emb,
    const float* __restrict__ pe, float* __restrict__ x,
    unsigned short* __restrict__ xb) {
  const int row = blockIdx.x;
  const int s = row & (SEQ - 1);
  const int tok = tokens[row];
  const int c = threadIdx.x * 4;
  float4 ev = *(const float4*)(emb + (size_t)tok * EDIM + c);
  float4 pv = *(const float4*)(pe + (size_t)s * EDIM + c);
  float4 o;
  o.x = ev.x + pv.x; o.y = ev.y + pv.y; o.z = ev.z + pv.z; o.w = ev.w + pv.w;
  *(float4*)(x + (size_t)row * EDIM + c) = o;
  unsigned short* xr = xb + (size_t)row * EDIM + c;
  xr[0] = f2bf(o.x); xr[1] = f2bf(o.y); xr[2] = f2bf(o.z); xr[3] = f2bf(o.w);
}

// ---------------- weight transpose+convert, layer-batched via blockIdx.z ----------------
__global__ __launch_bounds__(256) void transpose_w(
    const float* __restrict__ src0, unsigned short* __restrict__ dst0,
    int N, int K, float scale, size_t srcStride, size_t dstStride) {
  const float* src = src0 + (size_t)blockIdx.z * srcStride;
  unsigned short* dst = dst0 + (size_t)blockIdx.z * dstStride;
  __shared__ float tl[64][65];
  const int t = threadIdx.x;
  const int k0 = blockIdx.x * 64, n0 = blockIdx.y * 64;
  const int c = (t & 15) * 4, r0 = t >> 4;
  #pragma unroll
  for (int i = 0; i < 4; ++i) {
    const int r = r0 + i * 16;
    float4 v = *(const float4*)(src + (size_t)(k0 + r) * N + n0 + c);
    tl[r][c] = v.x; tl[r][c + 1] = v.y; tl[r][c + 2] = v.z; tl[r][c + 3] = v.w;
  }
  __syncthreads();
  #pragma unroll
  for (int i = 0; i < 4; ++i) {
    const int n = r0 + i * 16;
    uint2 o;
    o.x = (uint32_t)f2bf(tl[c + 0][n] * scale) | ((uint32_t)f2bf(tl[c + 1][n] * scale) << 16);
    o.y = (uint32_t)f2bf(tl[c + 2][n] * scale) | ((uint32_t)f2bf(tl[c + 3][n] * scale) << 16);
    *(uint2*)(dst + (size_t)(n0 + n) * K + k0 + c) = o;
  }
}

// ---------------- pack qkv bias (bq scaled by ALPHA) ----------------
__global__ __launch_bounds__(256) void pack_bias(
    const float* __restrict__ bq, const float* __restrict__ bk,
    const float* __restrict__ bv, float* __restrict__ dst) {
  const int idx = blockIdx.x * 256 + threadIdx.x;
  if (idx >= NLAYER * QKVLD) return;
  const int layer = idx / QKVLD, c = idx % QKVLD;
  float v;
  if (c < 1024)      v = bq[layer * 1024 + c] * ALPHA;
  else if (c < 2048) v = bk[layer * 1024 + c - 1024];
  else               v = bv[layer * 1024 + c - 2048];
  dst[idx] = v;
}

// ---------------- 3-deep pipelined GEMM, BK=32, counted vmcnt, supergrouped tiles ----------------
template<int BM, int OUT_BF16, int RELU, int SPLITK>
__global__ __launch_bounds__(BM * 2, (BM == 256) ? 2 : 3) void gemm3(
    const unsigned short* __restrict__ A, const unsigned short* __restrict__ Bt,
    const float* __restrict__ bias, void* __restrict__ Cout, void* __restrict__ C2,
    int Nld, int KLEN, int KLD, int NBLK, int G) {
  constexpr int BUFB = BM * 128;
  constexpr int ABYTES = BM * 64;
  constexpr int WN = (BM == 256) ? 4 : 2;
  constexpr int MF = BM / 32;
  __shared__ __attribute__((aligned(16))) char smb[3 * BUFB];
  const int t = threadIdx.x, lane = t & 63;
  const int wave = t >> 6;
  const int wr = wave / WN, wc = wave % WN;
  const int l15 = lane & 15, lg = lane >> 4;

  const int cpx = gridDim.x >> 3;
  const int bid = blockIdx.x;
  const int swz = (bid & 7) * cpx + (bid >> 3);
  const int sg = (gridDim.x / NBLK) * G;
  const int ns = swz / sg, rem = swz % sg;
  const int m0 = (rem / G) * BM;
  const int n0 = (ns * G + rem % G) * BM;
  const int koff = SPLITK ? blockIdx.y * KLEN : 0;

  f32x4 acc[MF][4];
  #pragma unroll
  for (int i = 0; i < MF; ++i)
    #pragma unroll
    for (int j = 0; j < 4; ++j)
      acc[i][j] = (f32x4){0.f, 0.f, 0.f, 0.f};

  const int srow = t >> 2;
  const int scol = (((t & 3) ^ ((t >> 3) & 3)) << 3);
  const unsigned short* agp = A  + (size_t)(m0 + srow) * KLD + scol + koff;
  const unsigned short* bgp = Bt + (size_t)(n0 + srow) * KLD + scol + koff;
  const size_t rhalf = (size_t)(BM / 2) * KLD;

  const int cxo = (lg * 16) ^ (((l15 >> 1) & 3) << 4);
  const int rdA = (wr * (BM / 2) + l15) * 64 + cxo;
  const int rdB = ABYTES + (wc * 64 + l15) * 64 + cxo;

  auto stage_tile = [&](int b, int kt) {
    const int k0 = kt * 32;
    char* d = smb + b * BUFB + t * 16;
    gload16(agp + k0, d);
    gload16(agp + rhalf + k0, d + BM * 32);
    gload16(bgp + k0, d + ABYTES);
    gload16(bgp + rhalf + k0, d + ABYTES + BM * 32);
  };

  const int NT = KLEN / 32;
  stage_tile(0, 0);
  stage_tile(1, 1);
  asm volatile("s_waitcnt vmcnt(4)" ::: "memory");
  __builtin_amdgcn_s_barrier();
  __builtin_amdgcn_sched_barrier(0);

  int bufc = 0, bufn = 2;
  for (int tt = 0; tt < NT; ++tt) {
    if (tt + 2 < NT) stage_tile(bufn, tt + 2);

    const char* ab = smb + bufc * BUFB;
    bf16x8 af[MF], bf[4];
    #pragma unroll
    for (int mf = 0; mf < MF; ++mf)
      af[mf] = *(const bf16x8*)(ab + rdA + mf * 1024);
    #pragma unroll
    for (int nf = 0; nf < 4; ++nf)
      bf[nf] = *(const bf16x8*)(ab + rdB + nf * 1024);

    __builtin_amdgcn_s_setprio(1);
    #pragma unroll
    for (int mf = 0; mf < MF; ++mf)
      #pragma unroll
      for (int nf = 0; nf < 4; ++nf)
        acc[mf][nf] = __builtin_amdgcn_mfma_f32_16x16x32_bf16(af[mf], bf[nf], acc[mf][nf], 0, 0, 0);
    __builtin_amdgcn_s_setprio(0);

    if (tt + 2 < NT)      asm volatile("s_waitcnt vmcnt(4)" ::: "memory");
    else if (tt + 1 < NT) asm volatile("s_waitcnt vmcnt(0)" ::: "memory");
    __builtin_amdgcn_sched_barrier(0);
    __builtin_amdgcn_s_barrier();
    __builtin_amdgcn_sched_barrier(0);

    bufc = (bufc == 2) ? 0 : bufc + 1;
    bufn = (bufn == 2) ? 0 : bufn + 1;
  }

  void* Cw = (SPLITK && blockIdx.y) ? C2 : Cout;
  #pragma unroll
  for (int mf = 0; mf < MF; ++mf) {
    #pragma unroll
    for (int nf = 0; nf < 4; ++nf) {
      const int col = n0 + wc * 64 + nf * 16 + l15;
      const float bv = (SPLITK && blockIdx.y) ? 0.f : bias[col];
      #pragma unroll
      for (int r = 0; r < 4; ++r) {
        const int row = m0 + wr * (BM / 2) + mf * 16 + lg * 4 + r;
        float val = acc[mf][nf][r] + bv;
        if (RELU) val = fmaxf(val, 0.f);
        if (OUT_BF16)
          ((unsigned short*)Cw)[(size_t)row * Nld + col] = f2bf(val);
        else
          ((float*)Cw)[(size_t)row * Nld + col] = val;
      }
    }
  }
}

// ---------------- flash attention: swapped QK^T, 32 q-rows/wave, in-lane softmax ----------------
__global__ __launch_bounds__(256) void attn_kernel(
    const unsigned short* __restrict__ qkv, unsigned short* __restrict__ ctx) {
  const int b = blockIdx.z, h = blockIdx.y;
  const int t = threadIdx.x, wave = t >> 6, lane = t & 63;
  const int l15 = lane & 15, lg = lane >> 4;
  const int qBase = blockIdx.x * 128 + wave * 32;
  const unsigned short* qbs = qkv + (size_t)b * SEQ * QKVLD + h * DHEAD;
  const unsigned short* kbs = qbs + EDIM;
  const unsigned short* vbs = qbs + 2 * EDIM;
  __shared__ unsigned short Ksm[64][72];
  __shared__ unsigned short VTs[64 * 64];

  const unsigned short* qpA = qbs + (size_t)(qBase + l15) * QKVLD + lg * 8;
  const unsigned short* qpB = qbs + (size_t)(qBase + 16 + l15) * QKVLD + lg * 8;
  bf16x8 aA0 = *(const bf16x8*)qpA;
  bf16x8 aA1 = *(const bf16x8*)(qpA + 32);
  bf16x8 aB0 = *(const bf16x8*)qpB;
  bf16x8 aB1 = *(const bf16x8*)(qpB + 32);

  f32x4 oA[4], oB[4];
  #pragma unroll
  for (int dg = 0; dg < 4; ++dg) { oA[dg] = (f32x4){0,0,0,0}; oB[dg] = (f32x4){0,0,0,0}; }
  float mA = -1e30f, lsA = 0.f, mB = -1e30f, lsB = 0.f;

  const int sr = t >> 2;
  const int sc = (t & 3) * 16;
  const int posw = (((sr >> 4) & 1) << 5) | (((sr & 15) >> 2) << 3) | (((sr >> 5) & 1) << 2) | (sr & 3);
  const unsigned short* kgp = kbs + (size_t)sr * QKVLD + sc;
  const unsigned short* vgp = vbs + (size_t)sr * QKVLD + sc;
  const size_t tilestep = (size_t)64 * QKVLD;

  s16x8 kr0 = *(const s16x8*)kgp, kr1 = *(const s16x8*)(kgp + 8);
  s16x8 vr0 = *(const s16x8*)vgp, vr1 = *(const s16x8*)(vgp + 8);

  const int NT = SEQ / 64;
  for (int j = 0; j < NT; ++j) {
    *(s16x8*)&Ksm[sr][sc] = kr0;
    *(s16x8*)&Ksm[sr][sc + 8] = kr1;
    #pragma unroll
    for (int c = 0; c < 2; ++c) {
      s16x8 vv = c ? vr1 : vr0;
      #pragma unroll
      for (int e = 0; e < 8; ++e) {
        const int d = sc + c * 8 + e;
        const int byteo = d * 128 + ((posw * 2) ^ ((d & 7) << 4));
        *(unsigned short*)((char*)VTs + byteo) = (unsigned short)vv[e];
      }
    }
    __syncthreads();

    f32x4 sA[4], sB[4];
    __builtin_amdgcn_s_setprio(1);
    #pragma unroll
    for (int g = 0; g < 4; ++g) {
      bf16x8 k0 = *(const bf16x8*)&Ksm[g * 16 + l15][lg * 8];
      bf16x8 k1 = *(const bf16x8*)&Ksm[g * 16 + l15][32 + lg * 8];
      f32x4 zA = {0,0,0,0}, zB = {0,0,0,0};
      zA = __builtin_amdgcn_mfma_f32_16x16x32_bf16(k0, aA0, zA, 0, 0, 0);
      sA[g] = __builtin_amdgcn_mfma_f32_16x16x32_bf16(k1, aA1, zA, 0, 0, 0);
      zB = __builtin_amdgcn_mfma_f32_16x16x32_bf16(k0, aB0, zB, 0, 0, 0);
      sB[g] = __builtin_amdgcn_mfma_f32_16x16x32_bf16(k1, aB1, zB, 0, 0, 0);
    }
    __builtin_amdgcn_s_setprio(0);

    if (j + 1 < NT) {   // T14 reg prefetch
      const unsigned short* kn = kgp + (size_t)(j + 1) * tilestep;
      const unsigned short* vn = vgp + (size_t)(j + 1) * tilestep;
      kr0 = *(const s16x8*)kn; kr1 = *(const s16x8*)(kn + 8);
      vr0 = *(const s16x8*)vn; vr1 = *(const s16x8*)(vn + 8);
    }

    float mxA = sA[0][0], mxB = sB[0][0];
    #pragma unroll
    for (int g = 0; g < 4; ++g)
      #pragma unroll
      for (int r = 0; r < 4; ++r) { mxA = fmaxf(mxA, sA[g][r]); mxB = fmaxf(mxB, sB[g][r]); }
    mxA = fmaxf(mxA, __shfl_xor(mxA, 16)); mxA = fmaxf(mxA, __shfl_xor(mxA, 32));
    mxB = fmaxf(mxB, __shfl_xor(mxB, 16)); mxB = fmaxf(mxB, __shfl_xor(mxB, 32));

    if (__any((mxA > mA + 8.f) || (mxB > mB + 8.f))) {
      const float mnA = fmaxf(mA, mxA), mnB = fmaxf(mB, mxB);
      const float sclA = fexp2(mA - mnA), sclB = fexp2(mB - mnB);
      mA = mnA; mB = mnB;
      lsA *= sclA; lsB *= sclB;
      #pragma unroll
      for (int dg = 0; dg < 4; ++dg)
        #pragma unroll
        for (int r = 0; r < 4; ++r) { oA[dg][r] *= sclA; oB[dg][r] *= sclB; }
    }
    #pragma unroll
    for (int g = 0; g < 4; ++g)
      #pragma unroll
      for (int r = 0; r < 4; ++r) { sA[g][r] = fexp2(sA[g][r] - mA); sB[g][r] = fexp2(sB[g][r] - mB); }

    float rsA = 0.f, rsB = 0.f;
    #pragma unroll
    for (int g = 0; g < 4; ++g) {
      rsA += (sA[g][0] + sA[g][1]) + (sA[g][2] + sA[g][3]);
      rsB += (sB[g][0] + sB[g][1]) + (sB[g][2] + sB[g][3]);
    }
    rsA += __shfl_xor(rsA, 16); rsA += __shfl_xor(rsA, 32);
    rsB += __shfl_xor(rsB, 16); rsB += __shfl_xor(rsB, 32);
    lsA += rsA; lsB += rsB;

    union { uint32_t u[4]; bf16x8 v; } pA0, pA1, pB0, pB1;
    pA0.u[0] = cvtpk(sA[0][0], sA[0][1]); pA0.u[1] = cvtpk(sA[0][2], sA[0][3]);
    pA0.u[2] = cvtpk(sA[2][0], sA[2][1]); pA0.u[3] = cvtpk(sA[2][2], sA[2][3]);
    pA1.u[0] = cvtpk(sA[1][0], sA[1][1]); pA1.u[1] = cvtpk(sA[1][2], sA[1][3]);
    pA1.u[2] = cvtpk(sA[3][0], sA[3][1]); pA1.u[3] = cvtpk(sA[3][2], sA[3][3]);
    pB0.u[0] = cvtpk(sB[0][0], sB[0][1]); pB0.u[1] = cvtpk(sB[0][2], sB[0][3]);
    pB0.u[2] = cvtpk(sB[2][0], sB[2][1]); pB0.u[3] = cvtpk(sB[2][2], sB[2][3]);
    pB1.u[0] = cvtpk(sB[1][0], sB[1][1]); pB1.u[1] = cvtpk(sB[1][2], sB[1][3]);
    pB1.u[2] = cvtpk(sB[3][0], sB[3][1]); pB1.u[3] = cvtpk(sB[3][2], sB[3][3]);

    auto vld = [&](int dg, int c) {
      const int byteo = (dg * 16 + l15) * 128 + ((c * 64 + lg * 16) ^ ((l15 & 7) << 4));
      return *(const bf16x8*)((const char*)VTs + byteo);
    };
    __builtin_amdgcn_s_setprio(1);
    #pragma unroll
    for (int dg = 0; dg < 4; ++dg) {
      bf16x8 v0 = vld(dg, 0);
      oA[dg] = __builtin_amdgcn_mfma_f32_16x16x32_bf16(v0, pA0.v, oA[dg], 0, 0, 0);
      oB[dg] = __builtin_amdgcn_mfma_f32_16x16x32_bf16(v0, pB0.v, oB[dg], 0, 0, 0);
    }
    #pragma unroll
    for (int dg = 0; dg < 4; ++dg) {
      bf16x8 v1 = vld(dg, 1);
      oA[dg] = __builtin_amdgcn_mfma_f32_16x16x32_bf16(v1, pA1.v, oA[dg], 0, 0, 0);
      oB[dg] = __builtin_amdgcn_mfma_f32_16x16x32_bf16(v1, pB1.v, oB[dg], 0, 0, 0);
    }
    __builtin_amdgcn_s_setprio(0);
    __syncthreads();
  }

  unsigned short* base = ctx + (size_t)b * SEQ * EDIM + h * DHEAD;
  unsigned short* cpA = base + (size_t)(qBase + l15) * EDIM;
  unsigned short* cpB = base + (size_t)(qBase + 16 + l15) * EDIM;
  const float invA = 1.f / lsA, invB = 1.f / lsB;
  #pragma unroll
  for (int dg = 0; dg < 4; ++dg) {
    uint2 wA, wB;
    wA.x = cvtpk(oA[dg][0] * invA, oA[dg][1] * invA);
    wA.y = cvtpk(oA[dg][2] * invA, oA[dg][3] * invA);
    wB.x = cvtpk(oB[dg][0] * invB, oB[dg][1] * invB);
    wB.y = cvtpk(oB[dg][2] * invB, oB[dg][3] * invB);
    *(uint2*)(cpA + dg * 16 + lg * 4) = wA;
    *(uint2*)(cpB + dg * 16 + lg * 4) = wB;
  }
}

// ---------------- residual + layernorm; bf16 inputs; TWO: sum a + a2 (split-K) ----------------
template<int TWO>
__global__ __launch_bounds__(256) void ln_add_kernel(
    const unsigned short* __restrict__ a, const unsigned short* __restrict__ a2,
    const float* __restrict__ g, const float* __restrict__ bb,
    float* __restrict__ x, unsigned short* __restrict__ xb) {
  const int row = blockIdx.x, t = threadIdx.x;
  ushort4 au = *(const ushort4*)(a + (size_t)row * EDIM + t * 4);
  float4 av;
  av.x = b2f(au.x); av.y = b2f(au.y); av.z = b2f(au.z); av.w = b2f(au.w);
  if (TWO) {
    ushort4 a2u = *(const ushort4*)(a2 + (size_t)row * EDIM + t * 4);
    av.x += b2f(a2u.x); av.y += b2f(a2u.y); av.z += b2f(a2u.z); av.w += b2f(a2u.w);
  }
  float s = av.x + av.y + av.z + av.w;
  float qq = av.x * av.x + av.y * av.y + av.z * av.z + av.w * av.w;
  #pragma unroll
  for (int off = 1; off < 64; off <<= 1) { s += __shfl_xor(s, off); qq += __shfl_xor(qq, off); }
  __shared__ float red[8];
  const int wv = t >> 6;
  if ((t & 63) == 0) { red[wv] = s; red[4 + wv] = qq; }
  __syncthreads();
  s = red[0] + red[1] + red[2] + red[3];
  qq = red[4] + red[5] + red[6] + red[7];
  const float mean = s * (1.f / EDIM);
  const float rstd = rsqrtf(qq * (1.f / EDIM) - mean * mean + EPSF);
  float4 gv = *(const float4*)(g + t * 4);
  float4 bv = *(const float4*)(bb + t * 4);
  float* xr = x + (size_t)row * EDIM;
  float4 xv = *(float4*)(xr + t * 4);
  float4 o;
  o.x = xv.x + (av.x - mean) * rstd * gv.x + bv.x;
  o.y = xv.y + (av.y - mean) * rstd * gv.y + bv.y;
  o.z = xv.z + (av.z - mean) * rstd * gv.z + bv.z;
  o.w = xv.w + (av.w - mean) * rstd * gv.w + bv.w;
  *(float4*)(xr + t * 4) = o;
  unsigned short* xbr = xb + (size_t)row * EDIM + t * 4;
  xbr[0] = f2bf(o.x); xbr[1] = f2bf(o.y); xbr[2] = f2bf(o.z); xbr[3] = f2bf(o.w);
}

// ---------------- final double layernorm -> bf16 ----------------
__global__ __launch_bounds__(256) void final_ln_kernel(
    const float* __restrict__ x, const float* __restrict__ g1, const float* __restrict__ b1,
    const float* __restrict__ g2, const float* __restrict__ b2,
    unsigned short* __restrict__ xb) {
  const int row = blockIdx.x, t = threadIdx.x;
  __shared__ float red[8];
  const int wv = t >> 6;
  const float* xr = x + (size_t)row * EDIM;
  float4 v = *(const float4*)(xr + t * 4);

  float s = v.x + v.y + v.z + v.w;
  float qq = v.x * v.x + v.y * v.y + v.z * v.z + v.w * v.w;
  #pragma unroll
  for (int off = 1; off < 64; off <<= 1) { s += __shfl_xor(s, off); qq += __shfl_xor(qq, off); }
  if ((t & 63) == 0) { red[wv] = s; red[4 + wv] = qq; }
  __syncthreads();
  s = red[0] + red[1] + red[2] + red[3];
  qq = red[4] + red[5] + red[6] + red[7];
  __syncthreads();
  float mean = s * (1.f / EDIM);
  float rstd = rsqrtf(qq * (1.f / EDIM) - mean * mean + EPSF);
  float4 g1v = *(const float4*)(g1 + t * 4);
  float4 b1v = *(const float4*)(b1 + t * 4);
  float4 tv;
  tv.x = (v.x - mean) * rstd * g1v.x + b1v.x;
  tv.y = (v.y - mean) * rstd * g1v.y + b1v.y;
  tv.z = (v.z - mean) * rstd * g1v.z + b1v.z;
  tv.w = (v.w - mean) * rstd * g1v.w + b1v.w;

  s = tv.x + tv.y + tv.z + tv.w;
  qq = tv.x * tv.x + tv.y * tv.y + tv.z * tv.z + tv.w * tv.w;
  #pragma unroll
  for (int off = 1; off < 64; off <<= 1) { s += __shfl_xor(s, off); qq += __shfl_xor(qq, off); }
  if ((t & 63) == 0) { red[wv] = s; red[4 + wv] = qq; }
  __syncthreads();
  s = red[0] + red[1] + red[2] + red[3];
  qq = red[4] + red[5] + red[6] + red[7];
  mean = s * (1.f / EDIM);
  rstd = rsqrtf(qq * (1.f / EDIM) - mean * mean + EPSF);
  float4 g2v = *(const float4*)(g2 + t * 4);
  float4 b2v = *(const float4*)(b2 + t * 4);
  unsigned short* o = xb + (size_t)row * EDIM + t * 4;
  o[0] = f2bf((tv.x - mean) * rstd * g2v.x + b2v.x);
  o[1] = f2bf((tv.y - mean) * rstd * g2v.y + b2v.y);
  o[2] = f2bf((tv.z - mean) * rstd * g2v.z + b2v.z);
  o[3] = f2bf((tv.w - mean) * rstd * g2v.w + b2v.w);
}

// ---------------- launch ----------------
extern "C" void kernel_launch(void* const* d_in, const int* in_sizes, int n_in,
                              void* d_out, int out_size, void* d_ws, size_t ws_size,
                              hipStream_t stream) {
  const int*   tokens = (const int*)d_in[0];
  const float* emb    = (const float*)d_in[1];
  const float* pe     = (const float*)d_in[2];
  const float* Wq     = (const float*)d_in[3];
  const float* Wk     = (const float*)d_in[4];
  const float* Wv     = (const float*)d_in[5];
  const float* Wo     = (const float*)d_in[6];
  const float* W1     = (const float*)d_in[7];
  const float* W2     = (const float*)d_in[8];
  const float* bq     = (const float*)d_in[9];
  const float* bk     = (const float*)d_in[10];
  const float* bv     = (const float*)d_in[11];
  const float* bo     = (const float*)d_in[12];
  const float* b1     = (const float*)d_in[13];
  const float* b2     = (const float*)d_in[14];
  const float* ln1_g  = (const float*)d_in[15];
  const float* ln1_b  = (const float*)d_in[16];
  const float* ln2_g  = (const float*)d_in[17];
  const float* ln2_b  = (const float*)d_in[18];
  const float* enc_g  = (const float*)d_in[19];
  const float* enc_b  = (const float*)d_in[20];
  const float* fin_g  = (const float*)d_in[21];
  const float* fin_b  = (const float*)d_in[22];
  const float* Wout   = (const float*)d_in[23];
  const float* bout   = (const float*)d_in[24];
  float* out = (float*)d_out;

  uint8_t* p = (uint8_t*)d_ws;
  auto alloc = [&](size_t bytes) {
    void* r = (void*)p;
    p += (bytes + 255) & ~(size_t)255;
    return r;
  };
  float*          x     = (float*)alloc((size_t)MROWS * EDIM * 4);
  unsigned short* xb    = (unsigned short*)alloc((size_t)MROWS * EDIM * 2);
  unsigned short* tbuf  = (unsigned short*)alloc((size_t)MROWS * EDIM * 2);
  unsigned short* tbuf2 = (unsigned short*)alloc((size_t)MROWS * EDIM * 2);
  unsigned short* qkv   = (unsigned short*)alloc((size_t)MROWS * QKVLD * 2);
  unsigned short* ctx   = (unsigned short*)alloc((size_t)MROWS * EDIM * 2);
  unsigned short* wlt   = (unsigned short*)alloc((size_t)NLAYER * 12 * 1024 * 1024 * 2);
  unsigned short* woutt = (unsigned short*)alloc((size_t)VOCAB * EDIM * 2);
  float*          bqkv  = (float*)alloc((size_t)NLAYER * QKVLD * 4);
  unsigned short* ff1   = qkv;  // alias: qkv+ctx dead when ff1 is live
  if ((size_t)(p - (uint8_t*)d_ws) > ws_size) return;

  const dim3 blk(256);
  const dim3 blk512(512);
  const size_t LW = (size_t)12 * 1024 * 1024;
  const size_t M1 = 1024 * 1024;

  transpose_w<<<dim3(16, 16, NLAYER), blk, 0, stream>>>(Wq, wlt,          1024, 1024, ALPHA, M1, LW);
  transpose_w<<<dim3(16, 16, NLAYER), blk, 0, stream>>>(Wk, wlt + M1,     1024, 1024, 1.0f,  M1, LW);
  transpose_w<<<dim3(16, 16, NLAYER), blk, 0, stream>>>(Wv, wlt + 2 * M1, 1024, 1024, 1.0f,  M1, LW);
  transpose_w<<<dim3(16, 16, NLAYER), blk, 0, stream>>>(Wo, wlt + 3 * M1, 1024, 1024, 1.0f,  M1, LW);
  transpose_w<<<dim3(16, 64, NLAYER), blk, 0, stream>>>(W1, wlt + 4 * M1, 4096, 1024, 1.0f, 4 * M1, LW);
  transpose_w<<<dim3(64, 16, NLAYER), blk, 0, stream>>>(W2, wlt + 8 * M1, 1024, 4096, 1.0f, 4 * M1, LW);
  transpose_w<<<dim3(16, 500), blk, 0, stream>>>(Wout, woutt, VOCAB, 1024, 1.0f, 0, 0);
  pack_bias<<<(NLAYER * QKVLD + 255) / 256, blk, 0, stream>>>(bq, bk, bv, bqkv);

  embed_kernel<<<MROWS, blk, 0, stream>>>(tokens, emb, pe, x, xb);

  const int MB2 = MROWS / 256;   // 16
  const int MB1 = MROWS / 128;   // 32
  for (int i = 0; i < NLAYER; ++i) {
    unsigned short* lb = wlt + (size_t)i * LW;
    gemm3<128, 1, 0, 0><<<MB1 * (QKVLD / 128), blk, 0, stream>>>(
        xb, lb, bqkv + (size_t)i * QKVLD, qkv, nullptr, QKVLD, EDIM, EDIM, QKVLD / 128, 8);
    attn_kernel<<<dim3(SEQ / 128, NHEAD, BATCH), blk, 0, stream>>>(qkv, ctx);
    gemm3<128, 1, 0, 1><<<dim3(MB1 * (EDIM / 128), 2), blk, 0, stream>>>(
        ctx, lb + 3 * M1, bo + i * EDIM, tbuf, tbuf2, EDIM, EDIM / 2, EDIM, EDIM / 128, 8);
    ln_add_kernel<1><<<MROWS, blk, 0, stream>>>(tbuf, tbuf2, ln1_g + i * EDIM, ln1_b + i * EDIM, x, xb);
    gemm3<128, 1, 1, 0><<<MB1 * (DFFDIM / 128), blk, 0, stream>>>(
        xb, lb + 4 * M1, b1 + i * DFFDIM, ff1, nullptr, DFFDIM, EDIM, EDIM, DFFDIM / 128, 8);
    gemm3<128, 1, 0, 1><<<dim3(MB1 * (EDIM / 128), 2), blk, 0, stream>>>(
        ff1, lb + 8 * M1, b2 + i * EDIM, tbuf, tbuf2, EDIM, DFFDIM / 2, DFFDIM, EDIM / 128, 8);
    ln_add_kernel<1><<<MROWS, blk, 0, stream>>>(tbuf, tbuf2, ln2_g + i * EDIM, ln2_b + i * EDIM, x, xb);
  }

  final_ln_kernel<<<MROWS, blk, 0, stream>>>(x, enc_g, enc_b, fin_g, fin_b, xb);
  // vocab GEMM: 256^2, G=5 (best measured)
  gemm3<256, 0, 0, 0><<<MB2 * (VOCAB / 256), blk512, 0, stream>>>(
      xb, woutt, bout, out, nullptr, VOCAB, EDIM, EDIM, VOCAB / 256, 5);
}

// Round 19
// 1231.515 us; speedup vs baseline: 1.0882x; 1.0270x over previous
//
#include <hip/hip_runtime.h>
#include <hip/hip_bf16.h>
#include <stdint.h>

#define EDIM 1024
#define DFFDIM 4096
#define NLAYER 4
#define BATCH 4
#define SEQ 1024
#define NHEAD 16
#define DHEAD 64
#define VOCAB 32000
#define MROWS (BATCH*SEQ)
#define QKVLD (3*EDIM)
#define EPSF 1e-6f
#define ALPHA 0.18033688011112043f   // 0.125 * log2(e): folded into Wq/bq

typedef float f32x4 __attribute__((ext_vector_type(4)));
typedef short s16x8 __attribute__((ext_vector_type(8)));
typedef __bf16 bf16x8 __attribute__((ext_vector_type(8)));

__device__ inline unsigned short f2bf(float f) {
  union { float f; uint32_t u; } v; v.f = f;
  uint32_t r = v.u + 0x7fffu + ((v.u >> 16) & 1u);
  return (unsigned short)(r >> 16);
}
__device__ __forceinline__ float b2f(unsigned short u) {
  union { uint32_t u; float f; } v; v.u = (uint32_t)u << 16; return v.f;
}

__device__ __forceinline__ float fexp2(float x) {
  float r; asm("v_exp_f32 %0, %1" : "=v"(r) : "v"(x)); return r;
}
__device__ __forceinline__ uint32_t cvtpk(float lo, float hi) {
  uint32_t r; asm("v_cvt_pk_bf16_f32 %0, %1, %2" : "=v"(r) : "v"(lo), "v"(hi)); return r;
}

__device__ __forceinline__ void gload16(const void* g, void* l) {
  __builtin_amdgcn_global_load_lds(
      (const __attribute__((address_space(1))) void*)g,
      (__attribute__((address_space(3))) void*)l, 16, 0, 0);
}

// ---------------- embedding + positional encoding -> bf16 residual ----------------
__global__ __launch_bounds__(256) void embed_kernel(
    const int* __restrict__ tokens, const float* __restrict__ emb,
    const float* __restrict__ pe, unsigned short* __restrict__ xb) {
  const int row = blockIdx.x;
  const int s = row & (SEQ - 1);
  const int tok = tokens[row];
  const int c = threadIdx.x * 4;
  float4 ev = *(const float4*)(emb + (size_t)tok * EDIM + c);
  float4 pv = *(const float4*)(pe + (size_t)s * EDIM + c);
  unsigned short* xr = xb + (size_t)row * EDIM + c;
  ushort4 o;
  o.x = f2bf(ev.x + pv.x); o.y = f2bf(ev.y + pv.y);
  o.z = f2bf(ev.z + pv.z); o.w = f2bf(ev.w + pv.w);
  *(ushort4*)xr = o;
}

// ---------------- weight transpose+convert, layer-batched via blockIdx.z ----------------
__global__ __launch_bounds__(256) void transpose_w(
    const float* __restrict__ src0, unsigned short* __restrict__ dst0,
    int N, int K, float scale, size_t srcStride, size_t dstStride) {
  const float* src = src0 + (size_t)blockIdx.z * srcStride;
  unsigned short* dst = dst0 + (size_t)blockIdx.z * dstStride;
  __shared__ float tl[64][65];
  const int t = threadIdx.x;
  const int k0 = blockIdx.x * 64, n0 = blockIdx.y * 64;
  const int c = (t & 15) * 4, r0 = t >> 4;
  #pragma unroll
  for (int i = 0; i < 4; ++i) {
    const int r = r0 + i * 16;
    float4 v = *(const float4*)(src + (size_t)(k0 + r) * N + n0 + c);
    tl[r][c] = v.x; tl[r][c + 1] = v.y; tl[r][c + 2] = v.z; tl[r][c + 3] = v.w;
  }
  __syncthreads();
  #pragma unroll
  for (int i = 0; i < 4; ++i) {
    const int n = r0 + i * 16;
    uint2 o;
    o.x = (uint32_t)f2bf(tl[c + 0][n] * scale) | ((uint32_t)f2bf(tl[c + 1][n] * scale) << 16);
    o.y = (uint32_t)f2bf(tl[c + 2][n] * scale) | ((uint32_t)f2bf(tl[c + 3][n] * scale) << 16);
    *(uint2*)(dst + (size_t)(n0 + n) * K + k0 + c) = o;
  }
}

// ---------------- pack qkv bias (bq scaled by ALPHA) ----------------
__global__ __launch_bounds__(256) void pack_bias(
    const float* __restrict__ bq, const float* __restrict__ bk,
    const float* __restrict__ bv, float* __restrict__ dst) {
  const int idx = blockIdx.x * 256 + threadIdx.x;
  if (idx >= NLAYER * QKVLD) return;
  const int layer = idx / QKVLD, c = idx % QKVLD;
  float v;
  if (c < 1024)      v = bq[layer * 1024 + c] * ALPHA;
  else if (c < 2048) v = bk[layer * 1024 + c - 1024];
  else               v = bv[layer * 1024 + c - 2048];
  dst[idx] = v;
}

// ---------------- 3-deep pipelined GEMM, BK=32, counted vmcnt, supergrouped tiles ----------------
template<int BM, int OUT_BF16, int RELU, int SPLITK>
__global__ __launch_bounds__(BM * 2, (BM == 256) ? 2 : 3) void gemm3(
    const unsigned short* __restrict__ A, const unsigned short* __restrict__ Bt,
    const float* __restrict__ bias, void* __restrict__ Cout, void* __restrict__ C2,
    int Nld, int KLEN, int KLD, int NBLK, int G) {
  constexpr int BUFB = BM * 128;
  constexpr int ABYTES = BM * 64;
  constexpr int WN = (BM == 256) ? 4 : 2;
  constexpr int MF = BM / 32;
  __shared__ __attribute__((aligned(16))) char smb[3 * BUFB];
  const int t = threadIdx.x, lane = t & 63;
  const int wave = t >> 6;
  const int wr = wave / WN, wc = wave % WN;
  const int l15 = lane & 15, lg = lane >> 4;

  const int cpx = gridDim.x >> 3;
  const int bid = blockIdx.x;
  const int swz = (bid & 7) * cpx + (bid >> 3);
  const int sg = (gridDim.x / NBLK) * G;
  const int ns = swz / sg, rem = swz % sg;
  const int m0 = (rem / G) * BM;
  const int n0 = (ns * G + rem % G) * BM;
  const int koff = SPLITK ? blockIdx.y * KLEN : 0;

  f32x4 acc[MF][4];
  #pragma unroll
  for (int i = 0; i < MF; ++i)
    #pragma unroll
    for (int j = 0; j < 4; ++j)
      acc[i][j] = (f32x4){0.f, 0.f, 0.f, 0.f};

  const int srow = t >> 2;
  const int scol = (((t & 3) ^ ((t >> 3) & 3)) << 3);
  const unsigned short* agp = A  + (size_t)(m0 + srow) * KLD + scol + koff;
  const unsigned short* bgp = Bt + (size_t)(n0 + srow) * KLD + scol + koff;
  const size_t rhalf = (size_t)(BM / 2) * KLD;

  const int cxo = (lg * 16) ^ (((l15 >> 1) & 3) << 4);
  const int rdA = (wr * (BM / 2) + l15) * 64 + cxo;
  const int rdB = ABYTES + (wc * 64 + l15) * 64 + cxo;

  auto stage_tile = [&](int b, int kt) {
    const int k0 = kt * 32;
    char* d = smb + b * BUFB + t * 16;
    gload16(agp + k0, d);
    gload16(agp + rhalf + k0, d + BM * 32);
    gload16(bgp + k0, d + ABYTES);
    gload16(bgp + rhalf + k0, d + ABYTES + BM * 32);
  };

  const int NT = KLEN / 32;
  stage_tile(0, 0);
  stage_tile(1, 1);
  asm volatile("s_waitcnt vmcnt(4)" ::: "memory");
  __builtin_amdgcn_s_barrier();
  __builtin_amdgcn_sched_barrier(0);

  int bufc = 0, bufn = 2;
  for (int tt = 0; tt < NT; ++tt) {
    if (tt + 2 < NT) stage_tile(bufn, tt + 2);

    const char* ab = smb + bufc * BUFB;
    bf16x8 af[MF], bf[4];
    #pragma unroll
    for (int mf = 0; mf < MF; ++mf)
      af[mf] = *(const bf16x8*)(ab + rdA + mf * 1024);
    #pragma unroll
    for (int nf = 0; nf < 4; ++nf)
      bf[nf] = *(const bf16x8*)(ab + rdB + nf * 1024);

    __builtin_amdgcn_s_setprio(1);
    #pragma unroll
    for (int mf = 0; mf < MF; ++mf)
      #pragma unroll
      for (int nf = 0; nf < 4; ++nf)
        acc[mf][nf] = __builtin_amdgcn_mfma_f32_16x16x32_bf16(af[mf], bf[nf], acc[mf][nf], 0, 0, 0);
    __builtin_amdgcn_s_setprio(0);

    if (tt + 2 < NT)      asm volatile("s_waitcnt vmcnt(4)" ::: "memory");
    else if (tt + 1 < NT) asm volatile("s_waitcnt vmcnt(0)" ::: "memory");
    __builtin_amdgcn_sched_barrier(0);
    __builtin_amdgcn_s_barrier();
    __builtin_amdgcn_sched_barrier(0);

    bufc = (bufc == 2) ? 0 : bufc + 1;
    bufn = (bufn == 2) ? 0 : bufn + 1;
  }

  void* Cw = (SPLITK && blockIdx.y) ? C2 : Cout;
  #pragma unroll
  for (int mf = 0; mf < MF; ++mf) {
    #pragma unroll
    for (int nf = 0; nf < 4; ++nf) {
      const int col = n0 + wc * 64 + nf * 16 + l15;
      const float bv = (SPLITK && blockIdx.y) ? 0.f : bias[col];
      #pragma unroll
      for (int r = 0; r < 4; ++r) {
        const int row = m0 + wr * (BM / 2) + mf * 16 + lg * 4 + r;
        float val = acc[mf][nf][r] + bv;
        if (RELU) val = fmaxf(val, 0.f);
        if (OUT_BF16)
          ((unsigned short*)Cw)[(size_t)row * Nld + col] = f2bf(val);
        else
          ((float*)Cw)[(size_t)row * Nld + col] = val;
      }
    }
  }
}

// ---------------- flash attention: swapped QK^T, 32 q-rows/wave, in-lane softmax ----------------
__global__ __launch_bounds__(256) void attn_kernel(
    const unsigned short* __restrict__ qkv, unsigned short* __restrict__ ctx) {
  const int b = blockIdx.z, h = blockIdx.y;
  const int t = threadIdx.x, wave = t >> 6, lane = t & 63;
  const int l15 = lane & 15, lg = lane >> 4;
  const int qBase = blockIdx.x * 128 + wave * 32;
  const unsigned short* qbs = qkv + (size_t)b * SEQ * QKVLD + h * DHEAD;
  const unsigned short* kbs = qbs + EDIM;
  const unsigned short* vbs = qbs + 2 * EDIM;
  __shared__ unsigned short Ksm[64][72];
  __shared__ unsigned short VTs[64 * 64];

  const unsigned short* qpA = qbs + (size_t)(qBase + l15) * QKVLD + lg * 8;
  const unsigned short* qpB = qbs + (size_t)(qBase + 16 + l15) * QKVLD + lg * 8;
  bf16x8 aA0 = *(const bf16x8*)qpA;
  bf16x8 aA1 = *(const bf16x8*)(qpA + 32);
  bf16x8 aB0 = *(const bf16x8*)qpB;
  bf16x8 aB1 = *(const bf16x8*)(qpB + 32);

  f32x4 oA[4], oB[4];
  #pragma unroll
  for (int dg = 0; dg < 4; ++dg) { oA[dg] = (f32x4){0,0,0,0}; oB[dg] = (f32x4){0,0,0,0}; }
  float mA = -1e30f, lsA = 0.f, mB = -1e30f, lsB = 0.f;

  const int sr = t >> 2;
  const int sc = (t & 3) * 16;
  const int posw = (((sr >> 4) & 1) << 5) | (((sr & 15) >> 2) << 3) | (((sr >> 5) & 1) << 2) | (sr & 3);
  const unsigned short* kgp = kbs + (size_t)sr * QKVLD + sc;
  const unsigned short* vgp = vbs + (size_t)sr * QKVLD + sc;
  const size_t tilestep = (size_t)64 * QKVLD;

  s16x8 kr0 = *(const s16x8*)kgp, kr1 = *(const s16x8*)(kgp + 8);
  s16x8 vr0 = *(const s16x8*)vgp, vr1 = *(const s16x8*)(vgp + 8);

  const int NT = SEQ / 64;
  for (int j = 0; j < NT; ++j) {
    *(s16x8*)&Ksm[sr][sc] = kr0;
    *(s16x8*)&Ksm[sr][sc + 8] = kr1;
    #pragma unroll
    for (int c = 0; c < 2; ++c) {
      s16x8 vv = c ? vr1 : vr0;
      #pragma unroll
      for (int e = 0; e < 8; ++e) {
        const int d = sc + c * 8 + e;
        const int byteo = d * 128 + ((posw * 2) ^ ((d & 7) << 4));
        *(unsigned short*)((char*)VTs + byteo) = (unsigned short)vv[e];
      }
    }
    __syncthreads();

    f32x4 sA[4], sB[4];
    __builtin_amdgcn_s_setprio(1);
    #pragma unroll
    for (int g = 0; g < 4; ++g) {
      bf16x8 k0 = *(const bf16x8*)&Ksm[g * 16 + l15][lg * 8];
      bf16x8 k1 = *(const bf16x8*)&Ksm[g * 16 + l15][32 + lg * 8];
      f32x4 zA = {0,0,0,0}, zB = {0,0,0,0};
      zA = __builtin_amdgcn_mfma_f32_16x16x32_bf16(k0, aA0, zA, 0, 0, 0);
      sA[g] = __builtin_amdgcn_mfma_f32_16x16x32_bf16(k1, aA1, zA, 0, 0, 0);
      zB = __builtin_amdgcn_mfma_f32_16x16x32_bf16(k0, aB0, zB, 0, 0, 0);
      sB[g] = __builtin_amdgcn_mfma_f32_16x16x32_bf16(k1, aB1, zB, 0, 0, 0);
    }
    __builtin_amdgcn_s_setprio(0);

    if (j + 1 < NT) {   // T14 reg prefetch
      const unsigned short* kn = kgp + (size_t)(j + 1) * tilestep;
      const unsigned short* vn = vgp + (size_t)(j + 1) * tilestep;
      kr0 = *(const s16x8*)kn; kr1 = *(const s16x8*)(kn + 8);
      vr0 = *(const s16x8*)vn; vr1 = *(const s16x8*)(vn + 8);
    }

    float mxA = sA[0][0], mxB = sB[0][0];
    #pragma unroll
    for (int g = 0; g < 4; ++g)
      #pragma unroll
      for (int r = 0; r < 4; ++r) { mxA = fmaxf(mxA, sA[g][r]); mxB = fmaxf(mxB, sB[g][r]); }
    mxA = fmaxf(mxA, __shfl_xor(mxA, 16)); mxA = fmaxf(mxA, __shfl_xor(mxA, 32));
    mxB = fmaxf(mxB, __shfl_xor(mxB, 16)); mxB = fmaxf(mxB, __shfl_xor(mxB, 32));

    if (__any((mxA > mA + 8.f) || (mxB > mB + 8.f))) {
      const float mnA = fmaxf(mA, mxA), mnB = fmaxf(mB, mxB);
      const float sclA = fexp2(mA - mnA), sclB = fexp2(mB - mnB);
      mA = mnA; mB = mnB;
      lsA *= sclA; lsB *= sclB;
      #pragma unroll
      for (int dg = 0; dg < 4; ++dg)
        #pragma unroll
        for (int r = 0; r < 4; ++r) { oA[dg][r] *= sclA; oB[dg][r] *= sclB; }
    }
    #pragma unroll
    for (int g = 0; g < 4; ++g)
      #pragma unroll
      for (int r = 0; r < 4; ++r) { sA[g][r] = fexp2(sA[g][r] - mA); sB[g][r] = fexp2(sB[g][r] - mB); }

    float rsA = 0.f, rsB = 0.f;
    #pragma unroll
    for (int g = 0; g < 4; ++g) {
      rsA += (sA[g][0] + sA[g][1]) + (sA[g][2] + sA[g][3]);
      rsB += (sB[g][0] + sB[g][1]) + (sB[g][2] + sB[g][3]);
    }
    rsA += __shfl_xor(rsA, 16); rsA += __shfl_xor(rsA, 32);
    rsB += __shfl_xor(rsB, 16); rsB += __shfl_xor(rsB, 32);
    lsA += rsA; lsB += rsB;

    union { uint32_t u[4]; bf16x8 v; } pA0, pA1, pB0, pB1;
    pA0.u[0] = cvtpk(sA[0][0], sA[0][1]); pA0.u[1] = cvtpk(sA[0][2], sA[0][3]);
    pA0.u[2] = cvtpk(sA[2][0], sA[2][1]); pA0.u[3] = cvtpk(sA[2][2], sA[2][3]);
    pA1.u[0] = cvtpk(sA[1][0], sA[1][1]); pA1.u[1] = cvtpk(sA[1][2], sA[1][3]);
    pA1.u[2] = cvtpk(sA[3][0], sA[3][1]); pA1.u[3] = cvtpk(sA[3][2], sA[3][3]);
    pB0.u[0] = cvtpk(sB[0][0], sB[0][1]); pB0.u[1] = cvtpk(sB[0][2], sB[0][3]);
    pB0.u[2] = cvtpk(sB[2][0], sB[2][1]); pB0.u[3] = cvtpk(sB[2][2], sB[2][3]);
    pB1.u[0] = cvtpk(sB[1][0], sB[1][1]); pB1.u[1] = cvtpk(sB[1][2], sB[1][3]);
    pB1.u[2] = cvtpk(sB[3][0], sB[3][1]); pB1.u[3] = cvtpk(sB[3][2], sB[3][3]);

    auto vld = [&](int dg, int c) {
      const int byteo = (dg * 16 + l15) * 128 + ((c * 64 + lg * 16) ^ ((l15 & 7) << 4));
      return *(const bf16x8*)((const char*)VTs + byteo);
    };
    __builtin_amdgcn_s_setprio(1);
    #pragma unroll
    for (int dg = 0; dg < 4; ++dg) {
      bf16x8 v0 = vld(dg, 0);
      oA[dg] = __builtin_amdgcn_mfma_f32_16x16x32_bf16(v0, pA0.v, oA[dg], 0, 0, 0);
      oB[dg] = __builtin_amdgcn_mfma_f32_16x16x32_bf16(v0, pB0.v, oB[dg], 0, 0, 0);
    }
    #pragma unroll
    for (int dg = 0; dg < 4; ++dg) {
      bf16x8 v1 = vld(dg, 1);
      oA[dg] = __builtin_amdgcn_mfma_f32_16x16x32_bf16(v1, pA1.v, oA[dg], 0, 0, 0);
      oB[dg] = __builtin_amdgcn_mfma_f32_16x16x32_bf16(v1, pB1.v, oB[dg], 0, 0, 0);
    }
    __builtin_amdgcn_s_setprio(0);
    __syncthreads();
  }

  unsigned short* base = ctx + (size_t)b * SEQ * EDIM + h * DHEAD;
  unsigned short* cpA = base + (size_t)(qBase + l15) * EDIM;
  unsigned short* cpB = base + (size_t)(qBase + 16 + l15) * EDIM;
  const float invA = 1.f / lsA, invB = 1.f / lsB;
  #pragma unroll
  for (int dg = 0; dg < 4; ++dg) {
    uint2 wA, wB;
    wA.x = cvtpk(oA[dg][0] * invA, oA[dg][1] * invA);
    wA.y = cvtpk(oA[dg][2] * invA, oA[dg][3] * invA);
    wB.x = cvtpk(oB[dg][0] * invB, oB[dg][1] * invB);
    wB.y = cvtpk(oB[dg][2] * invB, oB[dg][3] * invB);
    *(uint2*)(cpA + dg * 16 + lg * 4) = wA;
    *(uint2*)(cpB + dg * 16 + lg * 4) = wB;
  }
}

// ---------------- residual + layernorm; bf16 in/out, residual in place ----------------
template<int TWO>
__global__ __launch_bounds__(256) void ln_add_kernel(
    const unsigned short* __restrict__ a, const unsigned short* __restrict__ a2,
    const float* __restrict__ g, const float* __restrict__ bb,
    unsigned short* __restrict__ xb) {
  const int row = blockIdx.x, t = threadIdx.x;
  ushort4 au = *(const ushort4*)(a + (size_t)row * EDIM + t * 4);
  float4 av;
  av.x = b2f(au.x); av.y = b2f(au.y); av.z = b2f(au.z); av.w = b2f(au.w);
  if (TWO) {
    ushort4 a2u = *(const ushort4*)(a2 + (size_t)row * EDIM + t * 4);
    av.x += b2f(a2u.x); av.y += b2f(a2u.y); av.z += b2f(a2u.z); av.w += b2f(a2u.w);
  }
  float s = av.x + av.y + av.z + av.w;
  float qq = av.x * av.x + av.y * av.y + av.z * av.z + av.w * av.w;
  #pragma unroll
  for (int off = 1; off < 64; off <<= 1) { s += __shfl_xor(s, off); qq += __shfl_xor(qq, off); }
  __shared__ float red[8];
  const int wv = t >> 6;
  if ((t & 63) == 0) { red[wv] = s; red[4 + wv] = qq; }
  __syncthreads();
  s = red[0] + red[1] + red[2] + red[3];
  qq = red[4] + red[5] + red[6] + red[7];
  const float mean = s * (1.f / EDIM);
  const float rstd = rsqrtf(qq * (1.f / EDIM) - mean * mean + EPSF);
  float4 gv = *(const float4*)(g + t * 4);
  float4 bv = *(const float4*)(bb + t * 4);
  unsigned short* xr = xb + (size_t)row * EDIM + t * 4;
  ushort4 xu = *(ushort4*)xr;
  ushort4 o;
  o.x = f2bf(b2f(xu.x) + (av.x - mean) * rstd * gv.x + bv.x);
  o.y = f2bf(b2f(xu.y) + (av.y - mean) * rstd * gv.y + bv.y);
  o.z = f2bf(b2f(xu.z) + (av.z - mean) * rstd * gv.z + bv.z);
  o.w = f2bf(b2f(xu.w) + (av.w - mean) * rstd * gv.w + bv.w);
  *(ushort4*)xr = o;
}

// ---------------- final double layernorm (bf16 in, bf16 out in place) ----------------
__global__ __launch_bounds__(256) void final_ln_kernel(
    unsigned short* __restrict__ xb, const float* __restrict__ g1, const float* __restrict__ b1,
    const float* __restrict__ g2, const float* __restrict__ b2) {
  const int row = blockIdx.x, t = threadIdx.x;
  __shared__ float red[8];
  const int wv = t >> 6;
  unsigned short* xr = xb + (size_t)row * EDIM;
  ushort4 vu = *(const ushort4*)(xr + t * 4);
  float4 v;
  v.x = b2f(vu.x); v.y = b2f(vu.y); v.z = b2f(vu.z); v.w = b2f(vu.w);

  float s = v.x + v.y + v.z + v.w;
  float qq = v.x * v.x + v.y * v.y + v.z * v.z + v.w * v.w;
  #pragma unroll
  for (int off = 1; off < 64; off <<= 1) { s += __shfl_xor(s, off); qq += __shfl_xor(qq, off); }
  if ((t & 63) == 0) { red[wv] = s; red[4 + wv] = qq; }
  __syncthreads();
  s = red[0] + red[1] + red[2] + red[3];
  qq = red[4] + red[5] + red[6] + red[7];
  __syncthreads();
  float mean = s * (1.f / EDIM);
  float rstd = rsqrtf(qq * (1.f / EDIM) - mean * mean + EPSF);
  float4 g1v = *(const float4*)(g1 + t * 4);
  float4 b1v = *(const float4*)(b1 + t * 4);
  float4 tv;
  tv.x = (v.x - mean) * rstd * g1v.x + b1v.x;
  tv.y = (v.y - mean) * rstd * g1v.y + b1v.y;
  tv.z = (v.z - mean) * rstd * g1v.z + b1v.z;
  tv.w = (v.w - mean) * rstd * g1v.w + b1v.w;

  s = tv.x + tv.y + tv.z + tv.w;
  qq = tv.x * tv.x + tv.y * tv.y + tv.z * tv.z + tv.w * tv.w;
  #pragma unroll
  for (int off = 1; off < 64; off <<= 1) { s += __shfl_xor(s, off); qq += __shfl_xor(qq, off); }
  if ((t & 63) == 0) { red[wv] = s; red[4 + wv] = qq; }
  __syncthreads();
  s = red[0] + red[1] + red[2] + red[3];
  qq = red[4] + red[5] + red[6] + red[7];
  mean = s * (1.f / EDIM);
  rstd = rsqrtf(qq * (1.f / EDIM) - mean * mean + EPSF);
  float4 g2v = *(const float4*)(g2 + t * 4);
  float4 b2v = *(const float4*)(b2 + t * 4);
  ushort4 o;
  o.x = f2bf((tv.x - mean) * rstd * g2v.x + b2v.x);
  o.y = f2bf((tv.y - mean) * rstd * g2v.y + b2v.y);
  o.z = f2bf((tv.z - mean) * rstd * g2v.z + b2v.z);
  o.w = f2bf((tv.w - mean) * rstd * g2v.w + b2v.w);
  *(ushort4*)(xr + t * 4) = o;
}

// ---------------- launch ----------------
extern "C" void kernel_launch(void* const* d_in, const int* in_sizes, int n_in,
                              void* d_out, int out_size, void* d_ws, size_t ws_size,
                              hipStream_t stream) {
  const int*   tokens = (const int*)d_in[0];
  const float* emb    = (const float*)d_in[1];
  const float* pe     = (const float*)d_in[2];
  const float* Wq     = (const float*)d_in[3];
  const float* Wk     = (const float*)d_in[4];
  const float* Wv     = (const float*)d_in[5];
  const float* Wo     = (const float*)d_in[6];
  const float* W1     = (const float*)d_in[7];
  const float* W2     = (const float*)d_in[8];
  const float* bq     = (const float*)d_in[9];
  const float* bk     = (const float*)d_in[10];
  const float* bv     = (const float*)d_in[11];
  const float* bo     = (const float*)d_in[12];
  const float* b1     = (const float*)d_in[13];
  const float* b2     = (const float*)d_in[14];
  const float* ln1_g  = (const float*)d_in[15];
  const float* ln1_b  = (const float*)d_in[16];
  const float* ln2_g  = (const float*)d_in[17];
  const float* ln2_b  = (const float*)d_in[18];
  const float* enc_g  = (const float*)d_in[19];
  const float* enc_b  = (const float*)d_in[20];
  const float* fin_g  = (const float*)d_in[21];
  const float* fin_b  = (const float*)d_in[22];
  const float* Wout   = (const float*)d_in[23];
  const float* bout   = (const float*)d_in[24];
  float* out = (float*)d_out;

  uint8_t* p = (uint8_t*)d_ws;
  auto alloc = [&](size_t bytes) {
    void* r = (void*)p;
    p += (bytes + 255) & ~(size_t)255;
    return r;
  };
  unsigned short* xb    = (unsigned short*)alloc((size_t)MROWS * EDIM * 2);
  unsigned short* tbuf  = (unsigned short*)alloc((size_t)MROWS * EDIM * 2);
  unsigned short* tbuf2 = (unsigned short*)alloc((size_t)MROWS * EDIM * 2);
  unsigned short* qkv   = (unsigned short*)alloc((size_t)MROWS * QKVLD * 2);
  unsigned short* ctx   = (unsigned short*)alloc((size_t)MROWS * EDIM * 2);
  unsigned short* wlt   = (unsigned short*)alloc((size_t)NLAYER * 12 * 1024 * 1024 * 2);
  unsigned short* woutt = (unsigned short*)alloc((size_t)VOCAB * EDIM * 2);
  float*          bqkv  = (float*)alloc((size_t)NLAYER * QKVLD * 4);
  unsigned short* ff1   = qkv;  // alias: qkv+ctx dead when ff1 is live
  if ((size_t)(p - (uint8_t*)d_ws) > ws_size) return;

  const dim3 blk(256);
  const dim3 blk512(512);
  const size_t LW = (size_t)12 * 1024 * 1024;
  const size_t M1 = 1024 * 1024;

  transpose_w<<<dim3(16, 16, NLAYER), blk, 0, stream>>>(Wq, wlt,          1024, 1024, ALPHA, M1, LW);
  transpose_w<<<dim3(16, 16, NLAYER), blk, 0, stream>>>(Wk, wlt + M1,     1024, 1024, 1.0f,  M1, LW);
  transpose_w<<<dim3(16, 16, NLAYER), blk, 0, stream>>>(Wv, wlt + 2 * M1, 1024, 1024, 1.0f,  M1, LW);
  transpose_w<<<dim3(16, 16, NLAYER), blk, 0, stream>>>(Wo, wlt + 3 * M1, 1024, 1024, 1.0f,  M1, LW);
  transpose_w<<<dim3(16, 64, NLAYER), blk, 0, stream>>>(W1, wlt + 4 * M1, 4096, 1024, 1.0f, 4 * M1, LW);
  transpose_w<<<dim3(64, 16, NLAYER), blk, 0, stream>>>(W2, wlt + 8 * M1, 1024, 4096, 1.0f, 4 * M1, LW);
  transpose_w<<<dim3(16, 500), blk, 0, stream>>>(Wout, woutt, VOCAB, 1024, 1.0f, 0, 0);
  pack_bias<<<(NLAYER * QKVLD + 255) / 256, blk, 0, stream>>>(bq, bk, bv, bqkv);

  embed_kernel<<<MROWS, blk, 0, stream>>>(tokens, emb, pe, xb);

  const int MB2 = MROWS / 256;   // 16
  const int MB1 = MROWS / 128;   // 32
  for (int i = 0; i < NLAYER; ++i) {
    unsigned short* lb = wlt + (size_t)i * LW;
    gemm3<128, 1, 0, 0><<<MB1 * (QKVLD / 128), blk, 0, stream>>>(
        xb, lb, bqkv + (size_t)i * QKVLD, qkv, nullptr, QKVLD, EDIM, EDIM, QKVLD / 128, 8);
    attn_kernel<<<dim3(SEQ / 128, NHEAD, BATCH), blk, 0, stream>>>(qkv, ctx);
    gemm3<128, 1, 0, 1><<<dim3(MB1 * (EDIM / 128), 2), blk, 0, stream>>>(
        ctx, lb + 3 * M1, bo + i * EDIM, tbuf, tbuf2, EDIM, EDIM / 2, EDIM, EDIM / 128, 8);
    ln_add_kernel<1><<<MROWS, blk, 0, stream>>>(tbuf, tbuf2, ln1_g + i * EDIM, ln1_b + i * EDIM, xb);
    gemm3<128, 1, 1, 0><<<MB1 * (DFFDIM / 128), blk, 0, stream>>>(
        xb, lb + 4 * M1, b1 + i * DFFDIM, ff1, nullptr, DFFDIM, EDIM, EDIM, DFFDIM / 128, 8);
    gemm3<128, 1, 0, 1><<<dim3(MB1 * (EDIM / 128), 2), blk, 0, stream>>>(
        ff1, lb + 8 * M1, b2 + i * EDIM, tbuf, tbuf2, EDIM, DFFDIM / 2, DFFDIM, EDIM / 128, 8);
    ln_add_kernel<1><<<MROWS, blk, 0, stream>>>(tbuf, tbuf2, ln2_g + i * EDIM, ln2_b + i * EDIM, xb);
  }

  final_ln_kernel<<<MROWS, blk, 0, stream>>>(xb, enc_g, enc_b, fin_g, fin_b);
  // vocab GEMM: 256^2, G=5 (best measured)
  gemm3<256, 0, 0, 0><<<MB2 * (VOCAB / 256), blk512, 0, stream>>>(
      xb, woutt, bout, out, nullptr, VOCAB, EDIM, EDIM, VOCAB / 256, 5);
}

// Round 20
// 1230.504 us; speedup vs baseline: 1.0891x; 1.0008x over previous
//
#include <hip/hip_runtime.h>
#include <hip/hip_bf16.h>
#include <stdint.h>

#define EDIM 1024
#define DFFDIM 4096
#define NLAYER 4
#define BATCH 4
#define SEQ 1024
#define NHEAD 16
#define DHEAD 64
#define VOCAB 32000
#define MROWS (BATCH*SEQ)
#define QKVLD (3*EDIM)
#define EPSF 1e-6f
#define ALPHA 0.18033688011112043f   // 0.125 * log2(e): folded into Wq/bq

typedef float f32x4 __attribute__((ext_vector_type(4)));
typedef short s16x8 __attribute__((ext_vector_type(8)));
typedef __bf16 bf16x8 __attribute__((ext_vector_type(8)));

__device__ inline unsigned short f2bf(float f) {
  union { float f; uint32_t u; } v; v.f = f;
  uint32_t r = v.u + 0x7fffu + ((v.u >> 16) & 1u);
  return (unsigned short)(r >> 16);
}
__device__ __forceinline__ float b2f(unsigned short u) {
  union { uint32_t u; float f; } v; v.u = (uint32_t)u << 16; return v.f;
}

__device__ __forceinline__ float fexp2(float x) {
  float r; asm("v_exp_f32 %0, %1" : "=v"(r) : "v"(x)); return r;
}
__device__ __forceinline__ uint32_t cvtpk(float lo, float hi) {
  uint32_t r; asm("v_cvt_pk_bf16_f32 %0, %1, %2" : "=v"(r) : "v"(lo), "v"(hi)); return r;
}

__device__ __forceinline__ void gload16(const void* g, void* l) {
  __builtin_amdgcn_global_load_lds(
      (const __attribute__((address_space(1))) void*)g,
      (__attribute__((address_space(3))) void*)l, 16, 0, 0);
}

// ---------------- embedding + positional encoding -> bf16 residual ----------------
__global__ __launch_bounds__(256) void embed_kernel(
    const int* __restrict__ tokens, const float* __restrict__ emb,
    const float* __restrict__ pe, unsigned short* __restrict__ xb) {
  const int row = blockIdx.x;
  const int s = row & (SEQ - 1);
  const int tok = tokens[row];
  const int c = threadIdx.x * 4;
  float4 ev = *(const float4*)(emb + (size_t)tok * EDIM + c);
  float4 pv = *(const float4*)(pe + (size_t)s * EDIM + c);
  unsigned short* xr = xb + (size_t)row * EDIM + c;
  ushort4 o;
  o.x = f2bf(ev.x + pv.x); o.y = f2bf(ev.y + pv.y);
  o.z = f2bf(ev.z + pv.z); o.w = f2bf(ev.w + pv.w);
  *(ushort4*)xr = o;
}

// ---------------- weight transpose+convert, layer-batched via blockIdx.z ----------------
__global__ __launch_bounds__(256) void transpose_w(
    const float* __restrict__ src0, unsigned short* __restrict__ dst0,
    int N, int K, float scale, size_t srcStride, size_t dstStride) {
  const float* src = src0 + (size_t)blockIdx.z * srcStride;
  unsigned short* dst = dst0 + (size_t)blockIdx.z * dstStride;
  __shared__ float tl[64][65];
  const int t = threadIdx.x;
  const int k0 = blockIdx.x * 64, n0 = blockIdx.y * 64;
  const int c = (t & 15) * 4, r0 = t >> 4;
  #pragma unroll
  for (int i = 0; i < 4; ++i) {
    const int r = r0 + i * 16;
    float4 v = *(const float4*)(src + (size_t)(k0 + r) * N + n0 + c);
    tl[r][c] = v.x; tl[r][c + 1] = v.y; tl[r][c + 2] = v.z; tl[r][c + 3] = v.w;
  }
  __syncthreads();
  #pragma unroll
  for (int i = 0; i < 4; ++i) {
    const int n = r0 + i * 16;
    uint2 o;
    o.x = (uint32_t)f2bf(tl[c + 0][n] * scale) | ((uint32_t)f2bf(tl[c + 1][n] * scale) << 16);
    o.y = (uint32_t)f2bf(tl[c + 2][n] * scale) | ((uint32_t)f2bf(tl[c + 3][n] * scale) << 16);
    *(uint2*)(dst + (size_t)(n0 + n) * K + k0 + c) = o;
  }
}

// ---------------- pack qkv bias (bq scaled by ALPHA) ----------------
__global__ __launch_bounds__(256) void pack_bias(
    const float* __restrict__ bq, const float* __restrict__ bk,
    const float* __restrict__ bv, float* __restrict__ dst) {
  const int idx = blockIdx.x * 256 + threadIdx.x;
  if (idx >= NLAYER * QKVLD) return;
  const int layer = idx / QKVLD, c = idx % QKVLD;
  float v;
  if (c < 1024)      v = bq[layer * 1024 + c] * ALPHA;
  else if (c < 2048) v = bk[layer * 1024 + c - 1024];
  else               v = bv[layer * 1024 + c - 2048];
  dst[idx] = v;
}

// ---------------- 3-deep pipelined GEMM, BK=32, counted vmcnt, supergrouped tiles ----------------
template<int BM, int OUT_BF16, int RELU, int SPLITK>
__global__ __launch_bounds__(BM * 2, (BM == 256) ? 2 : 3) void gemm3(
    const unsigned short* __restrict__ A, const unsigned short* __restrict__ Bt,
    const float* __restrict__ bias, void* __restrict__ Cout, void* __restrict__ C2,
    int Nld, int KLEN, int KLD, int NBLK, int G) {
  constexpr int BUFB = BM * 128;
  constexpr int ABYTES = BM * 64;
  constexpr int WN = (BM == 256) ? 4 : 2;
  constexpr int MF = BM / 32;
  __shared__ __attribute__((aligned(16))) char smb[3 * BUFB];
  const int t = threadIdx.x, lane = t & 63;
  const int wave = t >> 6;
  const int wr = wave / WN, wc = wave % WN;
  const int l15 = lane & 15, lg = lane >> 4;

  const int cpx = gridDim.x >> 3;
  const int bid = blockIdx.x;
  const int swz = (bid & 7) * cpx + (bid >> 3);
  const int sg = (gridDim.x / NBLK) * G;
  const int ns = swz / sg, rem = swz % sg;
  const int m0 = (rem / G) * BM;
  const int n0 = (ns * G + rem % G) * BM;
  const int koff = SPLITK ? blockIdx.y * KLEN : 0;

  f32x4 acc[MF][4];
  #pragma unroll
  for (int i = 0; i < MF; ++i)
    #pragma unroll
    for (int j = 0; j < 4; ++j)
      acc[i][j] = (f32x4){0.f, 0.f, 0.f, 0.f};

  const int srow = t >> 2;
  const int scol = (((t & 3) ^ ((t >> 3) & 3)) << 3);
  const unsigned short* agp = A  + (size_t)(m0 + srow) * KLD + scol + koff;
  const unsigned short* bgp = Bt + (size_t)(n0 + srow) * KLD + scol + koff;
  const size_t rhalf = (size_t)(BM / 2) * KLD;

  const int cxo = (lg * 16) ^ (((l15 >> 1) & 3) << 4);
  const int rdA = (wr * (BM / 2) + l15) * 64 + cxo;
  const int rdB = ABYTES + (wc * 64 + l15) * 64 + cxo;

  auto stage_tile = [&](int b, int kt) {
    const int k0 = kt * 32;
    char* d = smb + b * BUFB + t * 16;
    gload16(agp + k0, d);
    gload16(agp + rhalf + k0, d + BM * 32);
    gload16(bgp + k0, d + ABYTES);
    gload16(bgp + rhalf + k0, d + ABYTES + BM * 32);
  };

  const int NT = KLEN / 32;
  stage_tile(0, 0);
  stage_tile(1, 1);
  asm volatile("s_waitcnt vmcnt(4)" ::: "memory");
  __builtin_amdgcn_s_barrier();
  __builtin_amdgcn_sched_barrier(0);

  int bufc = 0, bufn = 2;
  for (int tt = 0; tt < NT; ++tt) {
    if (tt + 2 < NT) stage_tile(bufn, tt + 2);

    const char* ab = smb + bufc * BUFB;
    bf16x8 af[MF], bf[4];
    #pragma unroll
    for (int mf = 0; mf < MF; ++mf)
      af[mf] = *(const bf16x8*)(ab + rdA + mf * 1024);
    #pragma unroll
    for (int nf = 0; nf < 4; ++nf)
      bf[nf] = *(const bf16x8*)(ab + rdB + nf * 1024);

    __builtin_amdgcn_s_setprio(1);
    #pragma unroll
    for (int mf = 0; mf < MF; ++mf)
      #pragma unroll
      for (int nf = 0; nf < 4; ++nf)
        acc[mf][nf] = __builtin_amdgcn_mfma_f32_16x16x32_bf16(af[mf], bf[nf], acc[mf][nf], 0, 0, 0);
    __builtin_amdgcn_s_setprio(0);

    if (tt + 2 < NT)      asm volatile("s_waitcnt vmcnt(4)" ::: "memory");
    else if (tt + 1 < NT) asm volatile("s_waitcnt vmcnt(0)" ::: "memory");
    __builtin_amdgcn_sched_barrier(0);
    __builtin_amdgcn_s_barrier();
    __builtin_amdgcn_sched_barrier(0);

    bufc = (bufc == 2) ? 0 : bufc + 1;
    bufn = (bufn == 2) ? 0 : bufn + 1;
  }

  void* Cw = (SPLITK && blockIdx.y) ? C2 : Cout;
  #pragma unroll
  for (int mf = 0; mf < MF; ++mf) {
    #pragma unroll
    for (int nf = 0; nf < 4; ++nf) {
      const int col = n0 + wc * 64 + nf * 16 + l15;
      const float bv = (SPLITK && blockIdx.y) ? 0.f : bias[col];
      #pragma unroll
      for (int r = 0; r < 4; ++r) {
        const int row = m0 + wr * (BM / 2) + mf * 16 + lg * 4 + r;
        float val = acc[mf][nf][r] + bv;
        if (RELU) val = fmaxf(val, 0.f);
        if (OUT_BF16)
          ((unsigned short*)Cw)[(size_t)row * Nld + col] = f2bf(val);
        else
          ((float*)Cw)[(size_t)row * Nld + col] = val;
      }
    }
  }
}

// ---------------- flash attention: swapped QK^T, 32 q/wave, K/V LDS dbuf (1 barrier/tile) ----------------
// Buffer rotation jb = j&1: tile j+2's write to buf b follows tile j+1's barrier, which all
// waves pass only after finishing tile j's reads of buf b -> trailing barrier removable.
__global__ __launch_bounds__(256) void attn_kernel(
    const unsigned short* __restrict__ qkv, unsigned short* __restrict__ ctx) {
  const int b = blockIdx.z, h = blockIdx.y;
  const int t = threadIdx.x, wave = t >> 6, lane = t & 63;
  const int l15 = lane & 15, lg = lane >> 4;
  const int qBase = blockIdx.x * 128 + wave * 32;
  const unsigned short* qbs = qkv + (size_t)b * SEQ * QKVLD + h * DHEAD;
  const unsigned short* kbs = qbs + EDIM;
  const unsigned short* vbs = qbs + 2 * EDIM;
  __shared__ unsigned short Ksm[2][64][72];
  __shared__ unsigned short VTs[2][64 * 64];

  const unsigned short* qpA = qbs + (size_t)(qBase + l15) * QKVLD + lg * 8;
  const unsigned short* qpB = qbs + (size_t)(qBase + 16 + l15) * QKVLD + lg * 8;
  bf16x8 aA0 = *(const bf16x8*)qpA;
  bf16x8 aA1 = *(const bf16x8*)(qpA + 32);
  bf16x8 aB0 = *(const bf16x8*)qpB;
  bf16x8 aB1 = *(const bf16x8*)(qpB + 32);

  f32x4 oA[4], oB[4];
  #pragma unroll
  for (int dg = 0; dg < 4; ++dg) { oA[dg] = (f32x4){0,0,0,0}; oB[dg] = (f32x4){0,0,0,0}; }
  float mA = -1e30f, lsA = 0.f, mB = -1e30f, lsB = 0.f;

  const int sr = t >> 2;
  const int sc = (t & 3) * 16;
  const int posw = (((sr >> 4) & 1) << 5) | (((sr & 15) >> 2) << 3) | (((sr >> 5) & 1) << 2) | (sr & 3);
  const unsigned short* kgp = kbs + (size_t)sr * QKVLD + sc;
  const unsigned short* vgp = vbs + (size_t)sr * QKVLD + sc;
  const size_t tilestep = (size_t)64 * QKVLD;

  s16x8 kr0 = *(const s16x8*)kgp, kr1 = *(const s16x8*)(kgp + 8);
  s16x8 vr0 = *(const s16x8*)vgp, vr1 = *(const s16x8*)(vgp + 8);

  const int NT = SEQ / 64;
  for (int j = 0; j < NT; ++j) {
    const int jb = j & 1;
    *(s16x8*)&Ksm[jb][sr][sc] = kr0;
    *(s16x8*)&Ksm[jb][sr][sc + 8] = kr1;
    #pragma unroll
    for (int c = 0; c < 2; ++c) {
      s16x8 vv = c ? vr1 : vr0;
      #pragma unroll
      for (int e = 0; e < 8; ++e) {
        const int d = sc + c * 8 + e;
        const int byteo = d * 128 + ((posw * 2) ^ ((d & 7) << 4));
        *(unsigned short*)((char*)VTs[jb] + byteo) = (unsigned short)vv[e];
      }
    }
    __syncthreads();

    f32x4 sA[4], sB[4];
    __builtin_amdgcn_s_setprio(1);
    #pragma unroll
    for (int g = 0; g < 4; ++g) {
      bf16x8 k0 = *(const bf16x8*)&Ksm[jb][g * 16 + l15][lg * 8];
      bf16x8 k1 = *(const bf16x8*)&Ksm[jb][g * 16 + l15][32 + lg * 8];
      f32x4 zA = {0,0,0,0}, zB = {0,0,0,0};
      zA = __builtin_amdgcn_mfma_f32_16x16x32_bf16(k0, aA0, zA, 0, 0, 0);
      sA[g] = __builtin_amdgcn_mfma_f32_16x16x32_bf16(k1, aA1, zA, 0, 0, 0);
      zB = __builtin_amdgcn_mfma_f32_16x16x32_bf16(k0, aB0, zB, 0, 0, 0);
      sB[g] = __builtin_amdgcn_mfma_f32_16x16x32_bf16(k1, aB1, zB, 0, 0, 0);
    }
    __builtin_amdgcn_s_setprio(0);

    if (j + 1 < NT) {   // T14 reg prefetch
      const unsigned short* kn = kgp + (size_t)(j + 1) * tilestep;
      const unsigned short* vn = vgp + (size_t)(j + 1) * tilestep;
      kr0 = *(const s16x8*)kn; kr1 = *(const s16x8*)(kn + 8);
      vr0 = *(const s16x8*)vn; vr1 = *(const s16x8*)(vn + 8);
    }

    float mxA = sA[0][0], mxB = sB[0][0];
    #pragma unroll
    for (int g = 0; g < 4; ++g)
      #pragma unroll
      for (int r = 0; r < 4; ++r) { mxA = fmaxf(mxA, sA[g][r]); mxB = fmaxf(mxB, sB[g][r]); }
    mxA = fmaxf(mxA, __shfl_xor(mxA, 16)); mxA = fmaxf(mxA, __shfl_xor(mxA, 32));
    mxB = fmaxf(mxB, __shfl_xor(mxB, 16)); mxB = fmaxf(mxB, __shfl_xor(mxB, 32));

    if (__any((mxA > mA + 8.f) || (mxB > mB + 8.f))) {
      const float mnA = fmaxf(mA, mxA), mnB = fmaxf(mB, mxB);
      const float sclA = fexp2(mA - mnA), sclB = fexp2(mB - mnB);
      mA = mnA; mB = mnB;
      lsA *= sclA; lsB *= sclB;
      #pragma unroll
      for (int dg = 0; dg < 4; ++dg)
        #pragma unroll
        for (int r = 0; r < 4; ++r) { oA[dg][r] *= sclA; oB[dg][r] *= sclB; }
    }
    #pragma unroll
    for (int g = 0; g < 4; ++g)
      #pragma unroll
      for (int r = 0; r < 4; ++r) { sA[g][r] = fexp2(sA[g][r] - mA); sB[g][r] = fexp2(sB[g][r] - mB); }

    float rsA = 0.f, rsB = 0.f;
    #pragma unroll
    for (int g = 0; g < 4; ++g) {
      rsA += (sA[g][0] + sA[g][1]) + (sA[g][2] + sA[g][3]);
      rsB += (sB[g][0] + sB[g][1]) + (sB[g][2] + sB[g][3]);
    }
    rsA += __shfl_xor(rsA, 16); rsA += __shfl_xor(rsA, 32);
    rsB += __shfl_xor(rsB, 16); rsB += __shfl_xor(rsB, 32);
    lsA += rsA; lsB += rsB;

    union { uint32_t u[4]; bf16x8 v; } pA0, pA1, pB0, pB1;
    pA0.u[0] = cvtpk(sA[0][0], sA[0][1]); pA0.u[1] = cvtpk(sA[0][2], sA[0][3]);
    pA0.u[2] = cvtpk(sA[2][0], sA[2][1]); pA0.u[3] = cvtpk(sA[2][2], sA[2][3]);
    pA1.u[0] = cvtpk(sA[1][0], sA[1][1]); pA1.u[1] = cvtpk(sA[1][2], sA[1][3]);
    pA1.u[2] = cvtpk(sA[3][0], sA[3][1]); pA1.u[3] = cvtpk(sA[3][2], sA[3][3]);
    pB0.u[0] = cvtpk(sB[0][0], sB[0][1]); pB0.u[1] = cvtpk(sB[0][2], sB[0][3]);
    pB0.u[2] = cvtpk(sB[2][0], sB[2][1]); pB0.u[3] = cvtpk(sB[2][2], sB[2][3]);
    pB1.u[0] = cvtpk(sB[1][0], sB[1][1]); pB1.u[1] = cvtpk(sB[1][2], sB[1][3]);
    pB1.u[2] = cvtpk(sB[3][0], sB[3][1]); pB1.u[3] = cvtpk(sB[3][2], sB[3][3]);

    auto vld = [&](int dg, int c) {
      const int byteo = (dg * 16 + l15) * 128 + ((c * 64 + lg * 16) ^ ((l15 & 7) << 4));
      return *(const bf16x8*)((const char*)VTs[jb] + byteo);
    };
    __builtin_amdgcn_s_setprio(1);
    #pragma unroll
    for (int dg = 0; dg < 4; ++dg) {
      bf16x8 v0 = vld(dg, 0);
      oA[dg] = __builtin_amdgcn_mfma_f32_16x16x32_bf16(v0, pA0.v, oA[dg], 0, 0, 0);
      oB[dg] = __builtin_amdgcn_mfma_f32_16x16x32_bf16(v0, pB0.v, oB[dg], 0, 0, 0);
    }
    #pragma unroll
    for (int dg = 0; dg < 4; ++dg) {
      bf16x8 v1 = vld(dg, 1);
      oA[dg] = __builtin_amdgcn_mfma_f32_16x16x32_bf16(v1, pA1.v, oA[dg], 0, 0, 0);
      oB[dg] = __builtin_amdgcn_mfma_f32_16x16x32_bf16(v1, pB1.v, oB[dg], 0, 0, 0);
    }
    __builtin_amdgcn_s_setprio(0);
    // no trailing barrier: dbuf rotation + next tile's leading barrier order the reuse
  }

  unsigned short* base = ctx + (size_t)b * SEQ * EDIM + h * DHEAD;
  unsigned short* cpA = base + (size_t)(qBase + l15) * EDIM;
  unsigned short* cpB = base + (size_t)(qBase + 16 + l15) * EDIM;
  const float invA = 1.f / lsA, invB = 1.f / lsB;
  #pragma unroll
  for (int dg = 0; dg < 4; ++dg) {
    uint2 wA, wB;
    wA.x = cvtpk(oA[dg][0] * invA, oA[dg][1] * invA);
    wA.y = cvtpk(oA[dg][2] * invA, oA[dg][3] * invA);
    wB.x = cvtpk(oB[dg][0] * invB, oB[dg][1] * invB);
    wB.y = cvtpk(oB[dg][2] * invB, oB[dg][3] * invB);
    *(uint2*)(cpA + dg * 16 + lg * 4) = wA;
    *(uint2*)(cpB + dg * 16 + lg * 4) = wB;
  }
}

// ---------------- residual + layernorm; bf16 in/out, residual in place ----------------
template<int TWO>
__global__ __launch_bounds__(256) void ln_add_kernel(
    const unsigned short* __restrict__ a, const unsigned short* __restrict__ a2,
    const float* __restrict__ g, const float* __restrict__ bb,
    unsigned short* __restrict__ xb) {
  const int row = blockIdx.x, t = threadIdx.x;
  ushort4 au = *(const ushort4*)(a + (size_t)row * EDIM + t * 4);
  float4 av;
  av.x = b2f(au.x); av.y = b2f(au.y); av.z = b2f(au.z); av.w = b2f(au.w);
  if (TWO) {
    ushort4 a2u = *(const ushort4*)(a2 + (size_t)row * EDIM + t * 4);
    av.x += b2f(a2u.x); av.y += b2f(a2u.y); av.z += b2f(a2u.z); av.w += b2f(a2u.w);
  }
  float s = av.x + av.y + av.z + av.w;
  float qq = av.x * av.x + av.y * av.y + av.z * av.z + av.w * av.w;
  #pragma unroll
  for (int off = 1; off < 64; off <<= 1) { s += __shfl_xor(s, off); qq += __shfl_xor(qq, off); }
  __shared__ float red[8];
  const int wv = t >> 6;
  if ((t & 63) == 0) { red[wv] = s; red[4 + wv] = qq; }
  __syncthreads();
  s = red[0] + red[1] + red[2] + red[3];
  qq = red[4] + red[5] + red[6] + red[7];
  const float mean = s * (1.f / EDIM);
  const float rstd = rsqrtf(qq * (1.f / EDIM) - mean * mean + EPSF);
  float4 gv = *(const float4*)(g + t * 4);
  float4 bv = *(const float4*)(bb + t * 4);
  unsigned short* xr = xb + (size_t)row * EDIM + t * 4;
  ushort4 xu = *(ushort4*)xr;
  ushort4 o;
  o.x = f2bf(b2f(xu.x) + (av.x - mean) * rstd * gv.x + bv.x);
  o.y = f2bf(b2f(xu.y) + (av.y - mean) * rstd * gv.y + bv.y);
  o.z = f2bf(b2f(xu.z) + (av.z - mean) * rstd * gv.z + bv.z);
  o.w = f2bf(b2f(xu.w) + (av.w - mean) * rstd * gv.w + bv.w);
  *(ushort4*)xr = o;
}

// ---------------- final double layernorm (bf16 in, bf16 out in place) ----------------
__global__ __launch_bounds__(256) void final_ln_kernel(
    unsigned short* __restrict__ xb, const float* __restrict__ g1, const float* __restrict__ b1,
    const float* __restrict__ g2, const float* __restrict__ b2) {
  const int row = blockIdx.x, t = threadIdx.x;
  __shared__ float red[8];
  const int wv = t >> 6;
  unsigned short* xr = xb + (size_t)row * EDIM;
  ushort4 vu = *(const ushort4*)(xr + t * 4);
  float4 v;
  v.x = b2f(vu.x); v.y = b2f(vu.y); v.z = b2f(vu.z); v.w = b2f(vu.w);

  float s = v.x + v.y + v.z + v.w;
  float qq = v.x * v.x + v.y * v.y + v.z * v.z + v.w * v.w;
  #pragma unroll
  for (int off = 1; off < 64; off <<= 1) { s += __shfl_xor(s, off); qq += __shfl_xor(qq, off); }
  if ((t & 63) == 0) { red[wv] = s; red[4 + wv] = qq; }
  __syncthreads();
  s = red[0] + red[1] + red[2] + red[3];
  qq = red[4] + red[5] + red[6] + red[7];
  __syncthreads();
  float mean = s * (1.f / EDIM);
  float rstd = rsqrtf(qq * (1.f / EDIM) - mean * mean + EPSF);
  float4 g1v = *(const float4*)(g1 + t * 4);
  float4 b1v = *(const float4*)(b1 + t * 4);
  float4 tv;
  tv.x = (v.x - mean) * rstd * g1v.x + b1v.x;
  tv.y = (v.y - mean) * rstd * g1v.y + b1v.y;
  tv.z = (v.z - mean) * rstd * g1v.z + b1v.z;
  tv.w = (v.w - mean) * rstd * g1v.w + b1v.w;

  s = tv.x + tv.y + tv.z + tv.w;
  qq = tv.x * tv.x + tv.y * tv.y + tv.z * tv.z + tv.w * tv.w;
  #pragma unroll
  for (int off = 1; off < 64; off <<= 1) { s += __shfl_xor(s, off); qq += __shfl_xor(qq, off); }
  if ((t & 63) == 0) { red[wv] = s; red[4 + wv] = qq; }
  __syncthreads();
  s = red[0] + red[1] + red[2] + red[3];
  qq = red[4] + red[5] + red[6] + red[7];
  mean = s * (1.f / EDIM);
  rstd = rsqrtf(qq * (1.f / EDIM) - mean * mean + EPSF);
  float4 g2v = *(const float4*)(g2 + t * 4);
  float4 b2v = *(const float4*)(b2 + t * 4);
  ushort4 o;
  o.x = f2bf((tv.x - mean) * rstd * g2v.x + b2v.x);
  o.y = f2bf((tv.y - mean) * rstd * g2v.y + b2v.y);
  o.z = f2bf((tv.z - mean) * rstd * g2v.z + b2v.z);
  o.w = f2bf((tv.w - mean) * rstd * g2v.w + b2v.w);
  *(ushort4*)(xr + t * 4) = o;
}

// ---------------- launch ----------------
extern "C" void kernel_launch(void* const* d_in, const int* in_sizes, int n_in,
                              void* d_out, int out_size, void* d_ws, size_t ws_size,
                              hipStream_t stream) {
  const int*   tokens = (const int*)d_in[0];
  const float* emb    = (const float*)d_in[1];
  const float* pe     = (const float*)d_in[2];
  const float* Wq     = (const float*)d_in[3];
  const float* Wk     = (const float*)d_in[4];
  const float* Wv     = (const float*)d_in[5];
  const float* Wo     = (const float*)d_in[6];
  const float* W1     = (const float*)d_in[7];
  const float* W2     = (const float*)d_in[8];
  const float* bq     = (const float*)d_in[9];
  const float* bk     = (const float*)d_in[10];
  const float* bv     = (const float*)d_in[11];
  const float* bo     = (const float*)d_in[12];
  const float* b1     = (const float*)d_in[13];
  const float* b2     = (const float*)d_in[14];
  const float* ln1_g  = (const float*)d_in[15];
  const float* ln1_b  = (const float*)d_in[16];
  const float* ln2_g  = (const float*)d_in[17];
  const float* ln2_b  = (const float*)d_in[18];
  const float* enc_g  = (const float*)d_in[19];
  const float* enc_b  = (const float*)d_in[20];
  const float* fin_g  = (const float*)d_in[21];
  const float* fin_b  = (const float*)d_in[22];
  const float* Wout   = (const float*)d_in[23];
  const float* bout   = (const float*)d_in[24];
  float* out = (float*)d_out;

  uint8_t* p = (uint8_t*)d_ws;
  auto alloc = [&](size_t bytes) {
    void* r = (void*)p;
    p += (bytes + 255) & ~(size_t)255;
    return r;
  };
  unsigned short* xb    = (unsigned short*)alloc((size_t)MROWS * EDIM * 2);
  unsigned short* tbuf  = (unsigned short*)alloc((size_t)MROWS * EDIM * 2);
  unsigned short* tbuf2 = (unsigned short*)alloc((size_t)MROWS * EDIM * 2);
  unsigned short* qkv   = (unsigned short*)alloc((size_t)MROWS * QKVLD * 2);
  unsigned short* ctx   = (unsigned short*)alloc((size_t)MROWS * EDIM * 2);
  unsigned short* wlt   = (unsigned short*)alloc((size_t)NLAYER * 12 * 1024 * 1024 * 2);
  unsigned short* woutt = (unsigned short*)alloc((size_t)VOCAB * EDIM * 2);
  float*          bqkv  = (float*)alloc((size_t)NLAYER * QKVLD * 4);
  unsigned short* ff1   = qkv;  // alias: qkv+ctx dead when ff1 is live
  if ((size_t)(p - (uint8_t*)d_ws) > ws_size) return;

  const dim3 blk(256);
  const dim3 blk512(512);
  const size_t LW = (size_t)12 * 1024 * 1024;
  const size_t M1 = 1024 * 1024;

  transpose_w<<<dim3(16, 16, NLAYER), blk, 0, stream>>>(Wq, wlt,          1024, 1024, ALPHA, M1, LW);
  transpose_w<<<dim3(16, 16, NLAYER), blk, 0, stream>>>(Wk, wlt + M1,     1024, 1024, 1.0f,  M1, LW);
  transpose_w<<<dim3(16, 16, NLAYER), blk, 0, stream>>>(Wv, wlt + 2 * M1, 1024, 1024, 1.0f,  M1, LW);
  transpose_w<<<dim3(16, 16, NLAYER), blk, 0, stream>>>(Wo, wlt + 3 * M1, 1024, 1024, 1.0f,  M1, LW);
  transpose_w<<<dim3(16, 64, NLAYER), blk, 0, stream>>>(W1, wlt + 4 * M1, 4096, 1024, 1.0f, 4 * M1, LW);
  transpose_w<<<dim3(64, 16, NLAYER), blk, 0, stream>>>(W2, wlt + 8 * M1, 1024, 4096, 1.0f, 4 * M1, LW);
  transpose_w<<<dim3(16, 500), blk, 0, stream>>>(Wout, woutt, VOCAB, 1024, 1.0f, 0, 0);
  pack_bias<<<(NLAYER * QKVLD + 255) / 256, blk, 0, stream>>>(bq, bk, bv, bqkv);

  embed_kernel<<<MROWS, blk, 0, stream>>>(tokens, emb, pe, xb);

  const int MB2 = MROWS / 256;   // 16
  const int MB1 = MROWS / 128;   // 32
  for (int i = 0; i < NLAYER; ++i) {
    unsigned short* lb = wlt + (size_t)i * LW;
    gemm3<128, 1, 0, 0><<<MB1 * (QKVLD / 128), blk, 0, stream>>>(
        xb, lb, bqkv + (size_t)i * QKVLD, qkv, nullptr, QKVLD, EDIM, EDIM, QKVLD / 128, 8);
    attn_kernel<<<dim3(SEQ / 128, NHEAD, BATCH), blk, 0, stream>>>(qkv, ctx);
    gemm3<128, 1, 0, 1><<<dim3(MB1 * (EDIM / 128), 2), blk, 0, stream>>>(
        ctx, lb + 3 * M1, bo + i * EDIM, tbuf, tbuf2, EDIM, EDIM / 2, EDIM, EDIM / 128, 8);
    ln_add_kernel<1><<<MROWS, blk, 0, stream>>>(tbuf, tbuf2, ln1_g + i * EDIM, ln1_b + i * EDIM, xb);
    gemm3<128, 1, 1, 0><<<MB1 * (DFFDIM / 128), blk, 0, stream>>>(
        xb, lb + 4 * M1, b1 + i * DFFDIM, ff1, nullptr, DFFDIM, EDIM, EDIM, DFFDIM / 128, 8);
    gemm3<128, 1, 0, 1><<<dim3(MB1 * (EDIM / 128), 2), blk, 0, stream>>>(
        ff1, lb + 8 * M1, b2 + i * EDIM, tbuf, tbuf2, EDIM, DFFDIM / 2, DFFDIM, EDIM / 128, 8);
    ln_add_kernel<1><<<MROWS, blk, 0, stream>>>(tbuf, tbuf2, ln2_g + i * EDIM, ln2_b + i * EDIM, xb);
  }

  final_ln_kernel<<<MROWS, blk, 0, stream>>>(xb, enc_g, enc_b, fin_g, fin_b);
  // vocab GEMM: 256^2, G=5 (best measured)
  gemm3<256, 0, 0, 0><<<MB2 * (VOCAB / 256), blk512, 0, stream>>>(
      xb, woutt, bout, out, nullptr, VOCAB, EDIM, EDIM, VOCAB / 256, 5);
}